// Round 1
// baseline (2418.279 us; speedup 1.0000x reference)
//
#include <hip/hip_runtime.h>
#include <math.h>

constexpr int N = 50000;     // nodes
constexpr int E = 100000;    // edges
constexpr int B = 256;       // graphs
constexpr int H = 64;
constexpr int DN = 110;

#define DEV __device__ __forceinline__

DEV float sigf(float x) { return 1.0f / (1.0f + expf(-x)); }

DEV unsigned fenc(float x) {
    unsigned u = __float_as_uint(x);
    return (u & 0x80000000u) ? ~u : (u | 0x80000000u);
}
DEV float fdec(unsigned u) {
    return (u & 0x80000000u) ? __uint_as_float(u & 0x7fffffffu) : __uint_as_float(~u);
}

// ---------------- generic helpers ----------------
__global__ void k_fill(float* p, float v, int n) {
    int i = blockIdx.x * 256 + threadIdx.x;
    if (i < n) p[i] = v;
}

// out[c*R + r] = in[r*C + c]   (in is R x C)
__global__ void k_transpose(const float* in, float* out, int R, int C) {
    int idx = blockIdx.x * 256 + threadIdx.x;
    if (idx < R * C) {
        int r = idx / C, c = idx % C;
        out[c * R + r] = in[idx];
    }
}

// ---------------- projection: x = relu(na @ W + b); h = x ----------------
__launch_bounds__(256)
__global__ void k_proj(const float* __restrict__ na, const float* __restrict__ W,
                       const float* __restrict__ b, float* __restrict__ x, float* __restrict__ h) {
    __shared__ float Ws[DN * 64];
    __shared__ float as[16][112];
    int tid = threadIdx.x;
    for (int i = tid; i < DN * 64; i += 256) Ws[i] = W[i];
    int n0 = blockIdx.x * 16;
    for (int i = tid; i < 16 * DN; i += 256) {
        int nn = i / DN, ii = i % DN;
        as[nn][ii] = na[(n0 + nn) * DN + ii];
    }
    __syncthreads();
    int o = tid & 63, ng = tid >> 6;
    float bo = b[o];
    for (int j = 0; j < 4; ++j) {
        int nn = ng * 4 + j;
        float acc = bo;
#pragma unroll 10
        for (int i = 0; i < DN; ++i) acc += as[nn][i] * Ws[i * 64 + o];
        float v = fmaxf(acc, 0.0f);
        int n = n0 + nn;
        x[n * 64 + o] = v;
        h[n * 64 + o] = v;
    }
}

// ---------------- edge features: [edge_attr(8), rbf(8), 1.0] -> (E,17) ----------------
__global__ void k_efeat(const float* __restrict__ ea, const float* __restrict__ el,
                        const float* __restrict__ centers, const float* __restrict__ beta,
                        float* __restrict__ ef) {
    int e = blockIdx.x * 256 + threadIdx.x;
    if (e >= E) return;
    float L = el[e];
#pragma unroll
    for (int j = 0; j < 8; ++j) ef[e * 17 + j] = ea[e * 8 + j];
#pragma unroll
    for (int j = 0; j < 8; ++j) {
        float d = L - centers[j];
        ef[e * 17 + 8 + j] = expf(-beta[j] * d * d);
    }
    ef[e * 17 + 16] = 1.0f;
}

// ---------------- agg init with conv bias ----------------
__global__ void k_agginit(float* __restrict__ agg, const float* __restrict__ conv_b) {
    int idx = blockIdx.x * 256 + threadIdx.x;
    if (idx < N * 64) agg[idx] = conv_b[idx & 63];
}

// ---------------- message GEMM + scatter-add ----------------
// m_e[o] = sum_{kk=0..16} coef_e[kk] * sum_i feat[src_e][i] * Bkk[i][o]
// Bkk = bond_W[kk] (64x64), B16 = bond_b, coef[16] = 1.0
__launch_bounds__(256)
__global__ void k_msg(const float* __restrict__ feat, const float* __restrict__ ef,
                      const float* __restrict__ bond_W, const float* __restrict__ bond_b,
                      const int* __restrict__ src, const int* __restrict__ dst,
                      float* __restrict__ agg) {
    __shared__ float fsT[64 * 68];  // [i][e], stride 68
    __shared__ float bs[64 * 68];   // [i][o], stride 68
    __shared__ float efs[64 * 17];  // [e][kk]
    __shared__ int dsts[64];

    int tid = threadIdx.x;
    int e0blk = blockIdx.x * 64;

    if (tid < 64) {
        int eg = e0blk + tid;
        dsts[tid] = (eg < E) ? dst[eg] : 0;
    }
    for (int i = tid; i < 64 * 17; i += 256) {
        int ee = i / 17, kk = i % 17;
        int eg = e0blk + ee;
        efs[i] = (eg < E) ? ef[eg * 17 + kk] : 0.0f;
    }
    // stage feat[src] transposed: thread -> (edge = tid/4, i-chunk = (tid%4)*16)
    {
        int e_l = tid >> 2;
        int eg = e0blk + e_l;
        int i0 = (tid & 3) * 16;
        float v[16];
        if (eg < E) {
            int s = src[eg];
            const float4* fp = (const float4*)(feat + s * 64 + i0);
            float4 a0 = fp[0], a1 = fp[1], a2 = fp[2], a3 = fp[3];
            v[0]=a0.x; v[1]=a0.y; v[2]=a0.z; v[3]=a0.w;
            v[4]=a1.x; v[5]=a1.y; v[6]=a1.z; v[7]=a1.w;
            v[8]=a2.x; v[9]=a2.y; v[10]=a2.z; v[11]=a2.w;
            v[12]=a3.x; v[13]=a3.y; v[14]=a3.z; v[15]=a3.w;
        } else {
#pragma unroll
            for (int j = 0; j < 16; ++j) v[j] = 0.0f;
        }
#pragma unroll
        for (int j = 0; j < 16; ++j) fsT[(i0 + j) * 68 + e_l] = v[j];
    }

    int o0 = (tid & 15) * 4;
    int e4 = (tid >> 4) * 4;
    float C[4][4] = {};

    for (int kk = 0; kk < 17; ++kk) {
        __syncthreads();  // previous bs consumers done (also covers fsT/efs staging at kk=0)
        {
            const float* Bsrc = (kk < 16) ? (bond_W + kk * 4096) : bond_b;
            int f0 = tid * 16;
            const float4* bp = (const float4*)(Bsrc + f0);
            float4 b0 = bp[0], b1 = bp[1], b2 = bp[2], b3 = bp[3];
            float* dp = &bs[(f0 >> 6) * 68 + (f0 & 63)];
            ((float4*)dp)[0] = b0; ((float4*)dp)[1] = b1;
            ((float4*)dp)[2] = b2; ((float4*)dp)[3] = b3;
        }
        __syncthreads();

        float t[4][4] = {};
#pragma unroll 8
        for (int i = 0; i < 64; ++i) {
            float4 a = *(const float4*)&fsT[i * 68 + e4];
            float4 bv = *(const float4*)&bs[i * 68 + o0];
            t[0][0] += a.x * bv.x; t[0][1] += a.x * bv.y; t[0][2] += a.x * bv.z; t[0][3] += a.x * bv.w;
            t[1][0] += a.y * bv.x; t[1][1] += a.y * bv.y; t[1][2] += a.y * bv.z; t[1][3] += a.y * bv.w;
            t[2][0] += a.z * bv.x; t[2][1] += a.z * bv.y; t[2][2] += a.z * bv.z; t[2][3] += a.z * bv.w;
            t[3][0] += a.w * bv.x; t[3][1] += a.w * bv.y; t[3][2] += a.w * bv.z; t[3][3] += a.w * bv.w;
        }
#pragma unroll
        for (int j = 0; j < 4; ++j) {
            float cf = efs[(e4 + j) * 17 + kk];
            C[j][0] += cf * t[j][0]; C[j][1] += cf * t[j][1];
            C[j][2] += cf * t[j][2]; C[j][3] += cf * t[j][3];
        }
    }

#pragma unroll
    for (int j = 0; j < 4; ++j) {
        int eg2 = e0blk + e4 + j;
        if (eg2 >= E) continue;
        float* ap = agg + dsts[e4 + j] * 64 + o0;
        atomicAdd(ap + 0, C[j][0]);
        atomicAdd(ap + 1, C[j][1]);
        atomicAdd(ap + 2, C[j][2]);
        atomicAdd(ap + 3, C[j][3]);
    }
}

// ---------------- GRU step: h = GRU(relu(agg), h) ----------------
__launch_bounds__(256)
__global__ void k_gru(const float* __restrict__ agg, float* __restrict__ h,
                      const float* __restrict__ WihT, const float* __restrict__ WhhT,
                      const float* __restrict__ bih, const float* __restrict__ bhh) {
    __shared__ float gx_s[16 * 64];
    __shared__ float h_s[16 * 64];
    int tid = threadIdx.x;
    int n0 = blockIdx.x * 16;
    for (int i = tid; i < 16 * 64; i += 256) {
        int nn = i >> 6, ii = i & 63;
        int n = n0 + nn;
        float a = (n < N) ? agg[n * 64 + ii] : 0.0f;
        gx_s[i] = fmaxf(a, 0.0f);
        h_s[i] = (n < N) ? h[n * 64 + ii] : 0.0f;
    }
    __syncthreads();
    int o = tid & 63, ng = tid >> 6;  // 4 groups x 4 nodes
    float air[4] = {}, aiz[4] = {}, ain[4] = {}, ahr[4] = {}, ahz[4] = {}, ahn[4] = {};
#pragma unroll 4
    for (int i = 0; i < 64; ++i) {
        float wr = WihT[i * 192 + o], wz = WihT[i * 192 + 64 + o], wn = WihT[i * 192 + 128 + o];
        float ur = WhhT[i * 192 + o], uz = WhhT[i * 192 + 64 + o], un = WhhT[i * 192 + 128 + o];
#pragma unroll
        for (int j = 0; j < 4; ++j) {
            float gx = gx_s[(ng * 4 + j) * 64 + i];
            float hh = h_s[(ng * 4 + j) * 64 + i];
            air[j] += gx * wr; aiz[j] += gx * wz; ain[j] += gx * wn;
            ahr[j] += hh * ur; ahz[j] += hh * uz; ahn[j] += hh * un;
        }
    }
    float br = bih[o], bz = bih[64 + o], bn = bih[128 + o];
    float cr = bhh[o], cz = bhh[64 + o], cn = bhh[128 + o];
#pragma unroll
    for (int j = 0; j < 4; ++j) {
        int n = n0 + ng * 4 + j;
        if (n >= N) continue;
        float r = sigf(air[j] + br + ahr[j] + cr);
        float z = sigf(aiz[j] + bz + ahz[j] + cz);
        float nn_ = tanhf(ain[j] + bn + r * (ahn[j] + cn));
        float hold = h_s[(ng * 4 + j) * 64 + o];
        h[n * 64 + o] = (1.0f - z) * nn_ + z * hold;
    }
}

// ---------------- graph bounds ----------------
__global__ void k_binit(int* gs, int* ge) {
    int g = threadIdx.x;
    if (g < B) { gs[g] = N; ge[g] = 0; }
}
__global__ void k_bounds(const int* __restrict__ ng, int* gs, int* ge) {
    int n = blockIdx.x * 256 + threadIdx.x;
    if (n < N) {
        int g = ng[n];
        atomicMin(&gs[g], n);
        atomicMax(&ge[g], n + 1);
    }
}

// ---------------- Set2Set: 2-layer LSTM, one block per sample ----------------
__launch_bounds__(256)
__global__ void k_lstm(float* __restrict__ h0, float* __restrict__ c0,
                       float* __restrict__ h1, float* __restrict__ c1,
                       float* __restrict__ q_star,
                       const float* __restrict__ W0T, const float* __restrict__ U0T,
                       const float* __restrict__ b0i, const float* __restrict__ b0h,
                       const float* __restrict__ W1T, const float* __restrict__ U1T,
                       const float* __restrict__ b1i, const float* __restrict__ b1h) {
    __shared__ float xb[256], hb[128], gb[512], h0n[128];
    int s = blockIdx.x, tid = threadIdx.x;
    xb[tid] = q_star[s * 256 + tid];
    if (tid < 128) hb[tid] = h0[s * 128 + tid];
    __syncthreads();
    // layer 0
    float g0 = b0i[tid] + b0h[tid];
    float g1 = b0i[tid + 256] + b0h[tid + 256];
    for (int i = 0; i < 256; ++i) {
        float x = xb[i];
        g0 += x * W0T[i * 512 + tid];
        g1 += x * W0T[i * 512 + tid + 256];
    }
    for (int i = 0; i < 128; ++i) {
        float hh = hb[i];
        g0 += hh * U0T[i * 512 + tid];
        g1 += hh * U0T[i * 512 + tid + 256];
    }
    gb[tid] = g0; gb[tid + 256] = g1;
    __syncthreads();
    if (tid < 128) {
        float ii = gb[tid], ff = gb[128 + tid], gg = gb[256 + tid], oo = gb[384 + tid];
        float c = sigf(ff) * c0[s * 128 + tid] + sigf(ii) * tanhf(gg);
        float hn = sigf(oo) * tanhf(c);
        c0[s * 128 + tid] = c; h0[s * 128 + tid] = hn; h0n[tid] = hn;
        hb[tid] = h1[s * 128 + tid];  // reuse hb for layer-1 hidden
    }
    __syncthreads();
    // layer 1
    float ga = b1i[tid] + b1h[tid];
    float gbv = b1i[tid + 256] + b1h[tid + 256];
    for (int i = 0; i < 128; ++i) {
        float x = h0n[i], hh = hb[i];
        ga  += x * W1T[i * 512 + tid]       + hh * U1T[i * 512 + tid];
        gbv += x * W1T[i * 512 + tid + 256] + hh * U1T[i * 512 + tid + 256];
    }
    gb[tid] = ga; gb[tid + 256] = gbv;
    __syncthreads();
    if (tid < 128) {
        float ii = gb[tid], ff = gb[128 + tid], gg = gb[256 + tid], oo = gb[384 + tid];
        float c = sigf(ff) * c1[s * 128 + tid] + sigf(ii) * tanhf(gg);
        float hn = sigf(oo) * tanhf(c);
        c1[s * 128 + tid] = c; h1[s * 128 + tid] = hn;
        q_star[s * 256 + tid] = hn;        // q half
        q_star[s * 256 + 128 + tid] = 0.f; // r half zeroed for scatter
    }
}

__global__ void k_afill(unsigned* emax, float* den) {
    int g = threadIdx.x;
    if (g < B) { emax[g] = fenc(-INFINITY); den[g] = 0.0f; }
}

// e[n] = dot(node_agg[n], q[g]);  node_agg = [h | x]
__launch_bounds__(256)
__global__ void k_e(const float* __restrict__ h, const float* __restrict__ x,
                    const float* __restrict__ q, const int* __restrict__ ngr,
                    float* __restrict__ e_out, unsigned* __restrict__ emax) {
    int node = blockIdx.x * 4 + (threadIdx.x >> 6);
    int lane = threadIdx.x & 63;
    if (node >= N) return;
    int g = ngr[node];
    float v = h[node * 64 + lane] * q[g * 128 + lane] + x[node * 64 + lane] * q[g * 128 + 64 + lane];
#pragma unroll
    for (int off = 32; off; off >>= 1) v += __shfl_xor(v, off, 64);
    if (lane == 0) {
        e_out[node] = v;
        atomicMax(&emax[g], fenc(v));
    }
}

__global__ void k_p(const float* __restrict__ e, const int* __restrict__ ngr,
                    const unsigned* __restrict__ emax, float* __restrict__ p, float* __restrict__ den) {
    int n = blockIdx.x * 256 + threadIdx.x;
    if (n >= N) return;
    int g = ngr[n];
    float pv = expf(e[n] - fdec(emax[g]));
    p[n] = pv;
    atomicAdd(&den[g], pv);
}

// r_out[g][d] = sum_{n in g} node_agg[n][d] * p[n] / den[g]  -> q_star[g][128+d]
__launch_bounds__(128)
__global__ void k_r(const float* __restrict__ h, const float* __restrict__ x,
                    const float* __restrict__ p, const float* __restrict__ den,
                    const int* __restrict__ gs, const int* __restrict__ ge,
                    float* __restrict__ q_star) {
    int g = blockIdx.x, d = threadIdx.x;
    int s0 = gs[g], s1 = ge[g];
    float acc = 0.0f;
    for (int n = s0; n < s1; ++n) {
        float na = (d < 64) ? h[n * 64 + d] : x[n * 64 + (d - 64)];
        acc += na * p[n];
    }
    q_star[g * 256 + 128 + d] = (s1 > s0) ? acc / den[g] : 0.0f;
}

// ---------------- head: sparsify + MLP + softmax, one block per sample ----------------
__launch_bounds__(256)
__global__ void k_head(const float* __restrict__ q_star,
                       const float* __restrict__ spW, const float* __restrict__ spb,
                       const float* __restrict__ pa,
                       const float* __restrict__ W1, const float* __restrict__ b1,
                       const float* __restrict__ W2, const float* __restrict__ b2,
                       const float* __restrict__ oW, const float* __restrict__ ob,
                       float* __restrict__ out) {
    __shared__ float row[256], buf0[512], buf1[512];
    int s = blockIdx.x, tid = threadIdx.x;
    row[tid] = q_star[s * 256 + tid];
    __syncthreads();
    float a = pa[0];
    float f0 = spb[tid], f1 = spb[tid + 256];
    for (int i = 0; i < 256; ++i) {
        float q = row[i];
        f0 += q * spW[i * 512 + tid];
        f1 += q * spW[i * 512 + tid + 256];
    }
    buf0[tid] = (f0 >= 0.0f) ? f0 : a * f0;
    buf0[tid + 256] = (f1 >= 0.0f) ? f1 : a * f1;
    __syncthreads();
    float g0 = b1[tid], g1 = b1[tid + 256];
    for (int i = 0; i < 512; ++i) {
        float v = buf0[i];
        g0 += v * W1[i * 512 + tid];
        g1 += v * W1[i * 512 + tid + 256];
    }
    buf1[tid] = fmaxf(g0, 0.0f);
    buf1[tid + 256] = fmaxf(g1, 0.0f);
    __syncthreads();
    float t0 = b2[tid], t1 = b2[tid + 256];
    for (int i = 0; i < 512; ++i) {
        float v = buf1[i];
        t0 += v * W2[i * 512 + tid];
        t1 += v * W2[i * 512 + tid + 256];
    }
    buf0[tid] = tanhf(t0);
    buf0[tid + 256] = tanhf(t1);
    __syncthreads();
    if (tid < 64) {
        float v = -INFINITY;
        if (tid < 54) {
            v = ob[tid];
            for (int i = 0; i < 512; ++i) v += buf0[i] * oW[i * 54 + tid];
        }
        float m = v;
#pragma unroll
        for (int off = 32; off; off >>= 1) m = fmaxf(m, __shfl_xor(m, off, 64));
        float ex = (tid < 54) ? expf(v - m) : 0.0f;
        float ssum = ex;
#pragma unroll
        for (int off = 32; off; off >>= 1) ssum += __shfl_xor(ssum, off, 64);
        if (tid < 54) out[s * 54 + tid] = ex / ssum;
    }
}

// ---------------- driver ----------------
extern "C" void kernel_launch(void* const* d_in, const int* in_sizes, int n_in,
                              void* d_out, int out_size, void* d_ws, size_t ws_size,
                              hipStream_t stream) {
    const float* node_attr = (const float*)d_in[0];
    const float* edge_attr = (const float*)d_in[1];
    const float* edge_len  = (const float*)d_in[2];
    const int*   src       = (const int*)d_in[3];
    const int*   dst       = (const int*)d_in[4];
    const int*   node_grph = (const int*)d_in[5];
    const float* proj_W    = (const float*)d_in[6];
    const float* proj_b    = (const float*)d_in[7];
    const float* centers   = (const float*)d_in[8];
    const float* beta      = (const float*)d_in[9];
    const float* bond_W    = (const float*)d_in[10];
    const float* bond_b    = (const float*)d_in[11];
    const float* conv_b    = (const float*)d_in[12];
    const float* gru_Wih   = (const float*)d_in[13];
    const float* gru_Whh   = (const float*)d_in[14];
    const float* gru_bih   = (const float*)d_in[15];
    const float* gru_bhh   = (const float*)d_in[16];
    const float* lWih0     = (const float*)d_in[17];
    const float* lWhh0     = (const float*)d_in[18];
    const float* lbih0     = (const float*)d_in[19];
    const float* lbhh0     = (const float*)d_in[20];
    const float* lWih1     = (const float*)d_in[21];
    const float* lWhh1     = (const float*)d_in[22];
    const float* lbih1     = (const float*)d_in[23];
    const float* lbhh1     = (const float*)d_in[24];
    const float* sp_W      = (const float*)d_in[25];
    const float* sp_b      = (const float*)d_in[26];
    const float* prelu_a   = (const float*)d_in[27];
    const float* h0_W1     = (const float*)d_in[28];
    const float* h0_b1     = (const float*)d_in[29];
    const float* h0_W2     = (const float*)d_in[30];
    const float* h0_b2     = (const float*)d_in[31];
    const float* out_W     = (const float*)d_in[32];
    const float* out_b     = (const float*)d_in[33];
    float* out = (float*)d_out;

    float* ws = (float*)d_ws;
    size_t off = 0;
    float* x      = ws + off; off += (size_t)N * 64;        // 3.2M
    float* h      = ws + off; off += (size_t)N * 64;
    float* ef     = ws + off; off += (size_t)E * 17;
    float* agg    = ws + off; off += (size_t)N * 64;
    float* gWihT  = ws + off; off += 64 * 192;
    float* gWhhT  = ws + off; off += 64 * 192;
    float* lW0T   = ws + off; off += 256 * 512;
    float* lU0T   = ws + off; off += 128 * 512;
    float* lW1T   = ws + off; off += 128 * 512;
    float* lU1T   = ws + off; off += 128 * 512;
    float* h0     = ws + off; off += B * 128;
    float* c0     = ws + off; off += B * 128;
    float* h1     = ws + off; off += B * 128;
    float* c1     = ws + off; off += B * 128;
    float* q_star = ws + off; off += B * 256;
    float* e_buf  = ws + off; off += N;
    float* p_buf  = ws + off; off += N;
    unsigned* emax = (unsigned*)(ws + off); off += B;
    float* den    = ws + off; off += B;
    int* gs       = (int*)(ws + off); off += B;
    int* ge       = (int*)(ws + off); off += B;

    // weight transposes (PyTorch (out,in) -> (in,out))
    k_transpose<<<(192 * 64 + 255) / 256, 256, 0, stream>>>(gru_Wih, gWihT, 192, 64);
    k_transpose<<<(192 * 64 + 255) / 256, 256, 0, stream>>>(gru_Whh, gWhhT, 192, 64);
    k_transpose<<<(512 * 256 + 255) / 256, 256, 0, stream>>>(lWih0, lW0T, 512, 256);
    k_transpose<<<(512 * 128 + 255) / 256, 256, 0, stream>>>(lWhh0, lU0T, 512, 128);
    k_transpose<<<(512 * 128 + 255) / 256, 256, 0, stream>>>(lWih1, lW1T, 512, 128);
    k_transpose<<<(512 * 128 + 255) / 256, 256, 0, stream>>>(lWhh1, lU1T, 512, 128);

    // zero LSTM state + q_star (contiguous region: h0,c0,h1,c1,q_star)
    k_fill<<<(4 * B * 128 + B * 256 + 255) / 256, 256, 0, stream>>>(h0, 0.0f, 4 * B * 128 + B * 256);

    k_proj<<<N / 16, 256, 0, stream>>>(node_attr, proj_W, proj_b, x, h);
    k_efeat<<<(E + 255) / 256, 256, 0, stream>>>(edge_attr, edge_len, centers, beta, ef);

    k_binit<<<1, 256, 0, stream>>>(gs, ge);
    k_bounds<<<(N + 255) / 256, 256, 0, stream>>>(node_grph, gs, ge);

    for (int step = 0; step < 4; ++step) {
        k_agginit<<<(N * 64 + 255) / 256, 256, 0, stream>>>(agg, conv_b);
        k_msg<<<(E + 63) / 64, 256, 0, stream>>>(h, ef, bond_W, bond_b, src, dst, agg);
        k_gru<<<(N + 15) / 16, 256, 0, stream>>>(agg, h, gWihT, gWhhT, gru_bih, gru_bhh);
    }

    for (int it = 0; it < 3; ++it) {
        k_lstm<<<B, 256, 0, stream>>>(h0, c0, h1, c1, q_star,
                                      lW0T, lU0T, lbih0, lbhh0,
                                      lW1T, lU1T, lbih1, lbhh1);
        k_afill<<<1, 256, 0, stream>>>(emax, den);
        k_e<<<(N + 3) / 4, 256, 0, stream>>>(h, x, h1, node_grph, e_buf, emax);
        k_p<<<(N + 255) / 256, 256, 0, stream>>>(e_buf, node_grph, emax, p_buf, den);
        k_r<<<B, 128, 0, stream>>>(h, x, p_buf, den, gs, ge, q_star);
    }

    k_head<<<B, 256, 0, stream>>>(q_star, sp_W, sp_b, prelu_a,
                                  h0_W1, h0_b1, h0_W2, h0_b2, out_W, out_b, out);
}

// Round 2
// 1692.409 us; speedup vs baseline: 1.4289x; 1.4289x over previous
//
#include <hip/hip_runtime.h>
#include <math.h>

constexpr int N = 50000;     // nodes
constexpr int E = 100000;    // edges
constexpr int B = 256;       // graphs
constexpr int H = 64;
constexpr int DN = 110;

#define DEV __device__ __forceinline__

typedef __attribute__((ext_vector_type(8))) short short8;
typedef __attribute__((ext_vector_type(4))) float floatx4;

DEV float sigf(float x) { return 1.0f / (1.0f + expf(-x)); }

DEV unsigned fenc(float x) {
    unsigned u = __float_as_uint(x);
    return (u & 0x80000000u) ? ~u : (u | 0x80000000u);
}
DEV float fdec(unsigned u) {
    return (u & 0x80000000u) ? __uint_as_float(u & 0x7fffffffu) : __uint_as_float(~u);
}

// bf16 round-to-nearest-even conversion (manual, header-type-free)
DEV short f2bf(float f) {
    unsigned u = __float_as_uint(f);
    unsigned r = (u + 0x7fffu + ((u >> 16) & 1u)) >> 16;
    return (short)r;
}
DEV float bf2f(short s) { return __uint_as_float(((unsigned)(unsigned short)s) << 16); }

// ---------------- generic helpers ----------------
__global__ void k_fill(float* p, float v, int n) {
    int i = blockIdx.x * 256 + threadIdx.x;
    if (i < n) p[i] = v;
}

// out[c*R + r] = in[r*C + c]   (in is R x C)
__global__ void k_transpose(const float* in, float* out, int R, int C) {
    int idx = blockIdx.x * 256 + threadIdx.x;
    if (idx < R * C) {
        int r = idx / C, c = idx % C;
        out[c * R + r] = in[idx];
    }
}

// ---------------- projection: x = relu(na @ W + b); h = x ----------------
__launch_bounds__(256)
__global__ void k_proj(const float* __restrict__ na, const float* __restrict__ W,
                       const float* __restrict__ b, float* __restrict__ x, float* __restrict__ h) {
    __shared__ float Ws[DN * 64];
    __shared__ float as[16][112];
    int tid = threadIdx.x;
    for (int i = tid; i < DN * 64; i += 256) Ws[i] = W[i];
    int n0 = blockIdx.x * 16;
    for (int i = tid; i < 16 * DN; i += 256) {
        int nn = i / DN, ii = i % DN;
        as[nn][ii] = na[(n0 + nn) * DN + ii];
    }
    __syncthreads();
    int o = tid & 63, ng = tid >> 6;
    float bo = b[o];
    for (int j = 0; j < 4; ++j) {
        int nn = ng * 4 + j;
        float acc = bo;
#pragma unroll 10
        for (int i = 0; i < DN; ++i) acc += as[nn][i] * Ws[i * 64 + o];
        float v = fmaxf(acc, 0.0f);
        int n = n0 + nn;
        x[n * 64 + o] = v;
        h[n * 64 + o] = v;
    }
}

// ---------------- edge features -> transposed layout ef_t[kk][e], kk 0..16 ----------------
// kk 0..7 = edge_attr, 8..15 = rbf, 16 = 1.0 (bias slot)
__global__ void k_efeat(const float* __restrict__ ea, const float* __restrict__ el,
                        const float* __restrict__ centers, const float* __restrict__ beta,
                        float* __restrict__ ef_t) {
    int e = blockIdx.x * 256 + threadIdx.x;
    if (e >= E) return;
    float L = el[e];
#pragma unroll
    for (int j = 0; j < 8; ++j) ef_t[j * E + e] = ea[e * 8 + j];
#pragma unroll
    for (int j = 0; j < 8; ++j) {
        float d = L - centers[j];
        ef_t[(8 + j) * E + e] = expf(-beta[j] * d * d);
    }
    ef_t[16 * E + e] = 1.0f;
}

// ---------------- agg init with conv bias ----------------
__global__ void k_agginit(float* __restrict__ agg, const float* __restrict__ conv_b) {
    int idx = blockIdx.x * 256 + threadIdx.x;
    if (idx < N * 64) agg[idx] = conv_b[idx & 63];
}

// ---------------- precompute bond_W (+bond_b as kk=16) into MFMA B-fragment layout ----------------
// B frag for 16x16x32 bf16: lane holds B[k = quad*8+j][n = col], quad=lane>>4, col=lane&15.
// wf layout: slot t = (kk*4 + nt)*2 + ks ; element ((t*2+part)*64 + lane)*8 + j   (part 0=hi,1=lo)
__global__ void k_prepW(const float* __restrict__ bond_W, const float* __restrict__ bond_b,
                        short* __restrict__ wf) {
    int idx = blockIdx.x * 256 + threadIdx.x;
    if (idx >= 17 * 4 * 2 * 64) return;
    int lane = idx & 63;
    int t = idx >> 6;            // (kk*4+nt)*2+ks
    int ks = t & 1;
    int nt = (t >> 1) & 3;
    int kk = t >> 3;
    const float* S = (kk < 16) ? (bond_W + kk * 4096) : bond_b;
    int quad = lane >> 4, col = lane & 15;
    short hi[8], lo[8];
#pragma unroll
    for (int j = 0; j < 8; ++j) {
        int i = ks * 32 + quad * 8 + j;
        float v = S[i * 64 + nt * 16 + col];
        short hb = f2bf(v);
        hi[j] = hb;
        lo[j] = f2bf(v - bf2f(hb));
    }
    short* dh = wf + (((size_t)(t * 2 + 0) * 64 + lane) * 8);
    short* dl = wf + (((size_t)(t * 2 + 1) * 64 + lane) * 8);
#pragma unroll
    for (int j = 0; j < 8; ++j) { dh[j] = hi[j]; dl[j] = lo[j]; }
}

// ---------------- message GEMM via split-bf16 MFMA + scatter-add ----------------
// Per block: 64 edges (M), 64 outputs (N). 4 waves, wave nt handles N-slice nt*16..+15.
// m[e][o] = sum_kk ef[e][kk] * (feat[src_e] @ W_kk)[o]
__launch_bounds__(256)
__global__ void k_msg2(const float* __restrict__ feat, const float* __restrict__ ef_t,
                       const short* __restrict__ wf,
                       const int* __restrict__ src, const int* __restrict__ dst,
                       float* __restrict__ agg) {
    __shared__ float efs[17 * 64];   // [kk][e_local]
    __shared__ int srcs[64];
    __shared__ int dsts[64];

    int tid = threadIdx.x;
    int e0 = blockIdx.x * 64;
    int lane = tid & 63;
    int nt = tid >> 6;
    int quad = lane >> 4, col = lane & 15;

    if (tid < 64) {
        int eg = e0 + tid;
        srcs[tid] = (eg < E) ? src[eg] : 0;
        dsts[tid] = (eg < E) ? dst[eg] : 0;
    }
    for (int i = tid; i < 17 * 64; i += 256) {
        int kk = i >> 6, e = i & 63;
        int eg = e0 + e;
        efs[i] = (eg < E) ? ef_t[kk * E + eg] : 0.0f;  // pad edges: all-zero incl bias slot
    }
    __syncthreads();

    // ---- build A fragments (feat, split hi/lo) once; constant across kk ----
    // A layout: lane holds A[m = col][k = quad*8+j]; m-tile mt covers edges mt*16..+15
    short8 Ah[4][2], Al[4][2];
#pragma unroll
    for (int mt = 0; mt < 4; ++mt) {
        int s = srcs[mt * 16 + col];
        const float* fp = feat + (size_t)s * 64 + quad * 8;
#pragma unroll
        for (int ks = 0; ks < 2; ++ks) {
            float4 u0 = *(const float4*)(fp + ks * 32);
            float4 u1 = *(const float4*)(fp + ks * 32 + 4);
            float vv[8] = {u0.x, u0.y, u0.z, u0.w, u1.x, u1.y, u1.z, u1.w};
            short8 hi, lo;
#pragma unroll
            for (int j = 0; j < 8; ++j) {
                short hb = f2bf(vv[j]);
                hi[j] = hb;
                lo[j] = f2bf(vv[j] - bf2f(hb));
            }
            Ah[mt][ks] = hi;
            Al[mt][ks] = lo;
        }
    }

    const short8* Wf = (const short8*)wf;
    float C[4][4] = {};

    // preload B frags for kk=0
    int tb = nt * 2;  // (0*4+nt)*2
    short8 Bh0 = Wf[((tb + 0) * 2 + 0) * 64 + lane];
    short8 Bh1 = Wf[((tb + 1) * 2 + 0) * 64 + lane];
    short8 Bl0 = Wf[((tb + 0) * 2 + 1) * 64 + lane];
    short8 Bl1 = Wf[((tb + 1) * 2 + 1) * 64 + lane];

#pragma unroll 1
    for (int kk = 0; kk < 17; ++kk) {
        // prefetch next kk's B frags (kk=16 harmlessly reloads itself)
        int kn = (kk < 16) ? (kk + 1) : 16;
        int tn = (kn * 4 + nt) * 2;
        short8 nh0 = Wf[((tn + 0) * 2 + 0) * 64 + lane];
        short8 nh1 = Wf[((tn + 1) * 2 + 0) * 64 + lane];
        short8 nl0 = Wf[((tn + 0) * 2 + 1) * 64 + lane];
        short8 nl1 = Wf[((tn + 1) * 2 + 1) * 64 + lane];

#pragma unroll
        for (int mt = 0; mt < 4; ++mt) {
            floatx4 T = {0.0f, 0.0f, 0.0f, 0.0f};
            T = __builtin_amdgcn_mfma_f32_16x16x32_bf16(Ah[mt][0], Bh0, T, 0, 0, 0);
            T = __builtin_amdgcn_mfma_f32_16x16x32_bf16(Ah[mt][1], Bh1, T, 0, 0, 0);
            T = __builtin_amdgcn_mfma_f32_16x16x32_bf16(Al[mt][0], Bh0, T, 0, 0, 0);
            T = __builtin_amdgcn_mfma_f32_16x16x32_bf16(Al[mt][1], Bh1, T, 0, 0, 0);
            T = __builtin_amdgcn_mfma_f32_16x16x32_bf16(Ah[mt][0], Bl0, T, 0, 0, 0);
            T = __builtin_amdgcn_mfma_f32_16x16x32_bf16(Ah[mt][1], Bl1, T, 0, 0, 0);
            // C rows: e_local = mt*16 + quad*4 + r  (C/D layout col=lane&15,row=quad*4+r)
            float4 ef = *(const float4*)&efs[kk * 64 + mt * 16 + quad * 4];
            C[mt][0] += ef.x * T[0];
            C[mt][1] += ef.y * T[1];
            C[mt][2] += ef.z * T[2];
            C[mt][3] += ef.w * T[3];
        }
        Bh0 = nh0; Bh1 = nh1; Bl0 = nl0; Bl1 = nl1;
    }

    // ---- scatter-add epilogue ----
    int o = nt * 16 + col;
#pragma unroll
    for (int mt = 0; mt < 4; ++mt) {
#pragma unroll
        for (int r = 0; r < 4; ++r) {
            int e_l = mt * 16 + quad * 4 + r;
            if (e0 + e_l < E) {
                atomicAdd(agg + (size_t)dsts[e_l] * 64 + o, C[mt][r]);
            }
        }
    }
}

// ---------------- GRU step: h = GRU(relu(agg), h) ----------------
__launch_bounds__(256)
__global__ void k_gru(const float* __restrict__ agg, float* __restrict__ h,
                      const float* __restrict__ WihT, const float* __restrict__ WhhT,
                      const float* __restrict__ bih, const float* __restrict__ bhh) {
    __shared__ float gx_s[16 * 64];
    __shared__ float h_s[16 * 64];
    int tid = threadIdx.x;
    int n0 = blockIdx.x * 16;
    for (int i = tid; i < 16 * 64; i += 256) {
        int nn = i >> 6, ii = i & 63;
        int n = n0 + nn;
        float a = (n < N) ? agg[n * 64 + ii] : 0.0f;
        gx_s[i] = fmaxf(a, 0.0f);
        h_s[i] = (n < N) ? h[n * 64 + ii] : 0.0f;
    }
    __syncthreads();
    int o = tid & 63, ng = tid >> 6;  // 4 groups x 4 nodes
    float air[4] = {}, aiz[4] = {}, ain[4] = {}, ahr[4] = {}, ahz[4] = {}, ahn[4] = {};
#pragma unroll 4
    for (int i = 0; i < 64; ++i) {
        float wr = WihT[i * 192 + o], wz = WihT[i * 192 + 64 + o], wn = WihT[i * 192 + 128 + o];
        float ur = WhhT[i * 192 + o], uz = WhhT[i * 192 + 64 + o], un = WhhT[i * 192 + 128 + o];
#pragma unroll
        for (int j = 0; j < 4; ++j) {
            float gx = gx_s[(ng * 4 + j) * 64 + i];
            float hh = h_s[(ng * 4 + j) * 64 + i];
            air[j] += gx * wr; aiz[j] += gx * wz; ain[j] += gx * wn;
            ahr[j] += hh * ur; ahz[j] += hh * uz; ahn[j] += hh * un;
        }
    }
    float br = bih[o], bz = bih[64 + o], bn = bih[128 + o];
    float cr = bhh[o], cz = bhh[64 + o], cn = bhh[128 + o];
#pragma unroll
    for (int j = 0; j < 4; ++j) {
        int n = n0 + ng * 4 + j;
        if (n >= N) continue;
        float r = sigf(air[j] + br + ahr[j] + cr);
        float z = sigf(aiz[j] + bz + ahz[j] + cz);
        float nn_ = tanhf(ain[j] + bn + r * (ahn[j] + cn));
        float hold = h_s[(ng * 4 + j) * 64 + o];
        h[n * 64 + o] = (1.0f - z) * nn_ + z * hold;
    }
}

// ---------------- graph bounds ----------------
__global__ void k_binit(int* gs, int* ge) {
    int g = threadIdx.x;
    if (g < B) { gs[g] = N; ge[g] = 0; }
}
__global__ void k_bounds(const int* __restrict__ ng, int* gs, int* ge) {
    int n = blockIdx.x * 256 + threadIdx.x;
    if (n < N) {
        int g = ng[n];
        atomicMin(&gs[g], n);
        atomicMax(&ge[g], n + 1);
    }
}

// ---------------- Set2Set: 2-layer LSTM, one block per sample ----------------
// Also re-inits emax/den for the attention pass that follows.
__launch_bounds__(256)
__global__ void k_lstm(float* __restrict__ h0, float* __restrict__ c0,
                       float* __restrict__ h1, float* __restrict__ c1,
                       float* __restrict__ q_star,
                       const float* __restrict__ W0T, const float* __restrict__ U0T,
                       const float* __restrict__ b0i, const float* __restrict__ b0h,
                       const float* __restrict__ W1T, const float* __restrict__ U1T,
                       const float* __restrict__ b1i, const float* __restrict__ b1h,
                       unsigned* __restrict__ emax, float* __restrict__ den) {
    __shared__ float xb[256], hb[128], gb[512], h0n[128];
    int s = blockIdx.x, tid = threadIdx.x;
    if (tid == 0) { emax[s] = fenc(-INFINITY); den[s] = 0.0f; }
    xb[tid] = q_star[s * 256 + tid];
    if (tid < 128) hb[tid] = h0[s * 128 + tid];
    __syncthreads();
    // layer 0
    float g0 = b0i[tid] + b0h[tid];
    float g1 = b0i[tid + 256] + b0h[tid + 256];
    for (int i = 0; i < 256; ++i) {
        float x = xb[i];
        g0 += x * W0T[i * 512 + tid];
        g1 += x * W0T[i * 512 + tid + 256];
    }
    for (int i = 0; i < 128; ++i) {
        float hh = hb[i];
        g0 += hh * U0T[i * 512 + tid];
        g1 += hh * U0T[i * 512 + tid + 256];
    }
    gb[tid] = g0; gb[tid + 256] = g1;
    __syncthreads();
    if (tid < 128) {
        float ii = gb[tid], ff = gb[128 + tid], gg = gb[256 + tid], oo = gb[384 + tid];
        float c = sigf(ff) * c0[s * 128 + tid] + sigf(ii) * tanhf(gg);
        float hn = sigf(oo) * tanhf(c);
        c0[s * 128 + tid] = c; h0[s * 128 + tid] = hn; h0n[tid] = hn;
        hb[tid] = h1[s * 128 + tid];  // reuse hb for layer-1 hidden
    }
    __syncthreads();
    // layer 1
    float ga = b1i[tid] + b1h[tid];
    float gbv = b1i[tid + 256] + b1h[tid + 256];
    for (int i = 0; i < 128; ++i) {
        float x = h0n[i], hh = hb[i];
        ga  += x * W1T[i * 512 + tid]       + hh * U1T[i * 512 + tid];
        gbv += x * W1T[i * 512 + tid + 256] + hh * U1T[i * 512 + tid + 256];
    }
    gb[tid] = ga; gb[tid + 256] = gbv;
    __syncthreads();
    if (tid < 128) {
        float ii = gb[tid], ff = gb[128 + tid], gg = gb[256 + tid], oo = gb[384 + tid];
        float c = sigf(ff) * c1[s * 128 + tid] + sigf(ii) * tanhf(gg);
        float hn = sigf(oo) * tanhf(c);
        c1[s * 128 + tid] = c; h1[s * 128 + tid] = hn;
        q_star[s * 256 + tid] = hn;        // q half
        q_star[s * 256 + 128 + tid] = 0.f; // r half zeroed for scatter
    }
}

// e[n] = dot(node_agg[n], q[g]);  node_agg = [h | x]
__launch_bounds__(256)
__global__ void k_e(const float* __restrict__ h, const float* __restrict__ x,
                    const float* __restrict__ q, const int* __restrict__ ngr,
                    float* __restrict__ e_out, unsigned* __restrict__ emax) {
    int node = blockIdx.x * 4 + (threadIdx.x >> 6);
    int lane = threadIdx.x & 63;
    if (node >= N) return;
    int g = ngr[node];
    float v = h[node * 64 + lane] * q[g * 128 + lane] + x[node * 64 + lane] * q[g * 128 + 64 + lane];
#pragma unroll
    for (int off = 32; off; off >>= 1) v += __shfl_xor(v, off, 64);
    if (lane == 0) {
        e_out[node] = v;
        atomicMax(&emax[g], fenc(v));
    }
}

__global__ void k_p(const float* __restrict__ e, const int* __restrict__ ngr,
                    const unsigned* __restrict__ emax, float* __restrict__ p, float* __restrict__ den) {
    int n = blockIdx.x * 256 + threadIdx.x;
    if (n >= N) return;
    int g = ngr[n];
    float pv = expf(e[n] - fdec(emax[g]));
    p[n] = pv;
    atomicAdd(&den[g], pv);
}

// r_out[g][d] = sum_{n in g} node_agg[n][d] * p[n] / den[g]  -> q_star[g][128+d]
__launch_bounds__(512)
__global__ void k_r(const float* __restrict__ h, const float* __restrict__ x,
                    const float* __restrict__ p, const float* __restrict__ den,
                    const int* __restrict__ gs, const int* __restrict__ ge,
                    float* __restrict__ q_star) {
    __shared__ float red[512];
    int g = blockIdx.x;
    int tid = threadIdx.x;
    int d = tid & 127, c = tid >> 7;  // 4-way split over nodes
    int s0 = gs[g], s1 = ge[g];
    float acc = 0.0f;
    for (int n = s0 + c; n < s1; n += 4) {
        float na = (d < 64) ? h[n * 64 + d] : x[n * 64 + (d - 64)];
        acc += na * p[n];
    }
    red[tid] = acc;
    __syncthreads();
    if (tid < 128) {
        float tot = red[tid] + red[tid + 128] + red[tid + 256] + red[tid + 384];
        q_star[g * 256 + 128 + tid] = (s1 > s0) ? tot / den[g] : 0.0f;
    }
}

// ---------------- head: sparsify + MLP + softmax, one block per sample ----------------
__launch_bounds__(256)
__global__ void k_head(const float* __restrict__ q_star,
                       const float* __restrict__ spW, const float* __restrict__ spb,
                       const float* __restrict__ pa,
                       const float* __restrict__ W1, const float* __restrict__ b1,
                       const float* __restrict__ W2, const float* __restrict__ b2,
                       const float* __restrict__ oW, const float* __restrict__ ob,
                       float* __restrict__ out) {
    __shared__ float row[256], buf0[512], buf1[512];
    int s = blockIdx.x, tid = threadIdx.x;
    row[tid] = q_star[s * 256 + tid];
    __syncthreads();
    float a = pa[0];
    float f0 = spb[tid], f1 = spb[tid + 256];
    for (int i = 0; i < 256; ++i) {
        float q = row[i];
        f0 += q * spW[i * 512 + tid];
        f1 += q * spW[i * 512 + tid + 256];
    }
    buf0[tid] = (f0 >= 0.0f) ? f0 : a * f0;
    buf0[tid + 256] = (f1 >= 0.0f) ? f1 : a * f1;
    __syncthreads();
    float g0 = b1[tid], g1 = b1[tid + 256];
    for (int i = 0; i < 512; ++i) {
        float v = buf0[i];
        g0 += v * W1[i * 512 + tid];
        g1 += v * W1[i * 512 + tid + 256];
    }
    buf1[tid] = fmaxf(g0, 0.0f);
    buf1[tid + 256] = fmaxf(g1, 0.0f);
    __syncthreads();
    float t0 = b2[tid], t1 = b2[tid + 256];
    for (int i = 0; i < 512; ++i) {
        float v = buf1[i];
        t0 += v * W2[i * 512 + tid];
        t1 += v * W2[i * 512 + tid + 256];
    }
    buf0[tid] = tanhf(t0);
    buf0[tid + 256] = tanhf(t1);
    __syncthreads();
    if (tid < 64) {
        float v = -INFINITY;
        if (tid < 54) {
            v = ob[tid];
            for (int i = 0; i < 512; ++i) v += buf0[i] * oW[i * 54 + tid];
        }
        float m = v;
#pragma unroll
        for (int off = 32; off; off >>= 1) m = fmaxf(m, __shfl_xor(m, off, 64));
        float ex = (tid < 54) ? expf(v - m) : 0.0f;
        float ssum = ex;
#pragma unroll
        for (int off = 32; off; off >>= 1) ssum += __shfl_xor(ssum, off, 64);
        if (tid < 54) out[s * 54 + tid] = ex / ssum;
    }
}

// ---------------- driver ----------------
extern "C" void kernel_launch(void* const* d_in, const int* in_sizes, int n_in,
                              void* d_out, int out_size, void* d_ws, size_t ws_size,
                              hipStream_t stream) {
    const float* node_attr = (const float*)d_in[0];
    const float* edge_attr = (const float*)d_in[1];
    const float* edge_len  = (const float*)d_in[2];
    const int*   src       = (const int*)d_in[3];
    const int*   dst       = (const int*)d_in[4];
    const int*   node_grph = (const int*)d_in[5];
    const float* proj_W    = (const float*)d_in[6];
    const float* proj_b    = (const float*)d_in[7];
    const float* centers   = (const float*)d_in[8];
    const float* beta      = (const float*)d_in[9];
    const float* bond_W    = (const float*)d_in[10];
    const float* bond_b    = (const float*)d_in[11];
    const float* conv_b    = (const float*)d_in[12];
    const float* gru_Wih   = (const float*)d_in[13];
    const float* gru_Whh   = (const float*)d_in[14];
    const float* gru_bih   = (const float*)d_in[15];
    const float* gru_bhh   = (const float*)d_in[16];
    const float* lWih0     = (const float*)d_in[17];
    const float* lWhh0     = (const float*)d_in[18];
    const float* lbih0     = (const float*)d_in[19];
    const float* lbhh0     = (const float*)d_in[20];
    const float* lWih1     = (const float*)d_in[21];
    const float* lWhh1     = (const float*)d_in[22];
    const float* lbih1     = (const float*)d_in[23];
    const float* lbhh1     = (const float*)d_in[24];
    const float* sp_W      = (const float*)d_in[25];
    const float* sp_b      = (const float*)d_in[26];
    const float* prelu_a   = (const float*)d_in[27];
    const float* h0_W1     = (const float*)d_in[28];
    const float* h0_b1     = (const float*)d_in[29];
    const float* h0_W2     = (const float*)d_in[30];
    const float* h0_b2     = (const float*)d_in[31];
    const float* out_W     = (const float*)d_in[32];
    const float* out_b     = (const float*)d_in[33];
    float* out = (float*)d_out;

    float* ws = (float*)d_ws;
    size_t off = 0;
    float* x      = ws + off; off += (size_t)N * 64;
    float* h      = ws + off; off += (size_t)N * 64;
    float* ef_t   = ws + off; off += (size_t)E * 17;
    float* agg    = ws + off; off += (size_t)N * 64;
    float* wfrag  = ws + off; off += 17 * 16 * 64 * 8 / 2;  // 139264 shorts = 69632 floats
    float* gWihT  = ws + off; off += 64 * 192;
    float* gWhhT  = ws + off; off += 64 * 192;
    float* lW0T   = ws + off; off += 256 * 512;
    float* lU0T   = ws + off; off += 128 * 512;
    float* lW1T   = ws + off; off += 128 * 512;
    float* lU1T   = ws + off; off += 128 * 512;
    float* h0     = ws + off; off += B * 128;
    float* c0     = ws + off; off += B * 128;
    float* h1     = ws + off; off += B * 128;
    float* c1     = ws + off; off += B * 128;
    float* q_star = ws + off; off += B * 256;
    float* e_buf  = ws + off; off += N;
    float* p_buf  = ws + off; off += N;
    unsigned* emax = (unsigned*)(ws + off); off += B;
    float* den    = ws + off; off += B;
    int* gs       = (int*)(ws + off); off += B;
    int* ge       = (int*)(ws + off); off += B;

    // weight transposes (PyTorch (out,in) -> (in,out))
    k_transpose<<<(192 * 64 + 255) / 256, 256, 0, stream>>>(gru_Wih, gWihT, 192, 64);
    k_transpose<<<(192 * 64 + 255) / 256, 256, 0, stream>>>(gru_Whh, gWhhT, 192, 64);
    k_transpose<<<(512 * 256 + 255) / 256, 256, 0, stream>>>(lWih0, lW0T, 512, 256);
    k_transpose<<<(512 * 128 + 255) / 256, 256, 0, stream>>>(lWhh0, lU0T, 512, 128);
    k_transpose<<<(512 * 128 + 255) / 256, 256, 0, stream>>>(lWih1, lW1T, 512, 128);
    k_transpose<<<(512 * 128 + 255) / 256, 256, 0, stream>>>(lWhh1, lU1T, 512, 128);

    // bond weights -> split-bf16 MFMA fragment layout
    k_prepW<<<(17 * 4 * 2 * 64 + 255) / 256, 256, 0, stream>>>(bond_W, bond_b, (short*)wfrag);

    // zero LSTM state + q_star (contiguous region: h0,c0,h1,c1,q_star)
    k_fill<<<(4 * B * 128 + B * 256 + 255) / 256, 256, 0, stream>>>(h0, 0.0f, 4 * B * 128 + B * 256);

    k_proj<<<N / 16, 256, 0, stream>>>(node_attr, proj_W, proj_b, x, h);
    k_efeat<<<(E + 255) / 256, 256, 0, stream>>>(edge_attr, edge_len, centers, beta, ef_t);

    k_binit<<<1, 256, 0, stream>>>(gs, ge);
    k_bounds<<<(N + 255) / 256, 256, 0, stream>>>(node_grph, gs, ge);

    for (int step = 0; step < 4; ++step) {
        k_agginit<<<(N * 64 + 255) / 256, 256, 0, stream>>>(agg, conv_b);
        k_msg2<<<(E + 63) / 64, 256, 0, stream>>>(h, ef_t, (const short*)wfrag, src, dst, agg);
        k_gru<<<(N + 15) / 16, 256, 0, stream>>>(agg, h, gWihT, gWhhT, gru_bih, gru_bhh);
    }

    for (int it = 0; it < 3; ++it) {
        k_lstm<<<B, 256, 0, stream>>>(h0, c0, h1, c1, q_star,
                                      lW0T, lU0T, lbih0, lbhh0,
                                      lW1T, lU1T, lbih1, lbhh1, emax, den);
        k_e<<<(N + 3) / 4, 256, 0, stream>>>(h, x, h1, node_grph, e_buf, emax);
        k_p<<<(N + 255) / 256, 256, 0, stream>>>(e_buf, node_grph, emax, p_buf, den);
        k_r<<<B, 512, 0, stream>>>(h, x, p_buf, den, gs, ge, q_star);
    }

    k_head<<<B, 256, 0, stream>>>(q_star, sp_W, sp_b, prelu_a,
                                  h0_W1, h0_b1, h0_W2, h0_b2, out_W, out_b, out);
}

// Round 3
// 1172.138 us; speedup vs baseline: 2.0631x; 1.4439x over previous
//
#include <hip/hip_runtime.h>
#include <math.h>

constexpr int N = 50000;     // nodes
constexpr int E = 100000;    // edges
constexpr int B = 256;       // graphs
constexpr int H = 64;
constexpr int DN = 110;

#define DEV __device__ __forceinline__

typedef __attribute__((ext_vector_type(8))) short short8;
typedef __attribute__((ext_vector_type(4))) float floatx4;

DEV float sigf(float x) { return 1.0f / (1.0f + expf(-x)); }

DEV unsigned fenc(float x) {
    unsigned u = __float_as_uint(x);
    return (u & 0x80000000u) ? ~u : (u | 0x80000000u);
}
DEV float fdec(unsigned u) {
    return (u & 0x80000000u) ? __uint_as_float(u & 0x7fffffffu) : __uint_as_float(~u);
}

// bf16 round-to-nearest-even conversion (manual, header-type-free)
DEV short f2bf(float f) {
    unsigned u = __float_as_uint(f);
    unsigned r = (u + 0x7fffu + ((u >> 16) & 1u)) >> 16;
    return (short)r;
}
DEV float bf2f(short s) { return __uint_as_float(((unsigned)(unsigned short)s) << 16); }

// ---------------- generic helpers ----------------
__global__ void k_fill(float* p, float v, int n) {
    int i = blockIdx.x * 256 + threadIdx.x;
    if (i < n) p[i] = v;
}

// out[c*R + r] = in[r*C + c]   (in is R x C)
__global__ void k_transpose(const float* in, float* out, int R, int C) {
    int idx = blockIdx.x * 256 + threadIdx.x;
    if (idx < R * C) {
        int r = idx / C, c = idx % C;
        out[c * R + r] = in[idx];
    }
}

// ---------------- projection: x = relu(na @ W + b); h = x ----------------
__launch_bounds__(256)
__global__ void k_proj(const float* __restrict__ na, const float* __restrict__ W,
                       const float* __restrict__ b, float* __restrict__ x, float* __restrict__ h) {
    __shared__ float Ws[DN * 64];
    __shared__ float as[16][112];
    int tid = threadIdx.x;
    for (int i = tid; i < DN * 64; i += 256) Ws[i] = W[i];
    int n0 = blockIdx.x * 16;
    for (int i = tid; i < 16 * DN; i += 256) {
        int nn = i / DN, ii = i % DN;
        as[nn][ii] = na[(n0 + nn) * DN + ii];
    }
    __syncthreads();
    int o = tid & 63, ng = tid >> 6;
    float bo = b[o];
    for (int j = 0; j < 4; ++j) {
        int nn = ng * 4 + j;
        float acc = bo;
#pragma unroll 10
        for (int i = 0; i < DN; ++i) acc += as[nn][i] * Ws[i * 64 + o];
        float v = fmaxf(acc, 0.0f);
        int n = n0 + nn;
        x[n * 64 + o] = v;
        h[n * 64 + o] = v;
    }
}

// ---------------- edge features -> transposed layout ef_t[kk][e], kk 0..16 ----------------
__global__ void k_efeat(const float* __restrict__ ea, const float* __restrict__ el,
                        const float* __restrict__ centers, const float* __restrict__ beta,
                        float* __restrict__ ef_t) {
    int e = blockIdx.x * 256 + threadIdx.x;
    if (e >= E) return;
    float L = el[e];
#pragma unroll
    for (int j = 0; j < 8; ++j) ef_t[j * E + e] = ea[e * 8 + j];
#pragma unroll
    for (int j = 0; j < 8; ++j) {
        float d = L - centers[j];
        ef_t[(8 + j) * E + e] = expf(-beta[j] * d * d);
    }
    ef_t[16 * E + e] = 1.0f;
}

// ---------------- agg init with conv bias ----------------
__global__ void k_agginit(float* __restrict__ agg, const float* __restrict__ conv_b) {
    int idx = blockIdx.x * 256 + threadIdx.x;
    if (idx < N * 64) agg[idx] = conv_b[idx & 63];
}

// ---------------- precompute bond_W (+bond_b as kk=16) into MFMA B-fragment layout ----------------
__global__ void k_prepW(const float* __restrict__ bond_W, const float* __restrict__ bond_b,
                        short* __restrict__ wf) {
    int idx = blockIdx.x * 256 + threadIdx.x;
    if (idx >= 17 * 4 * 2 * 64) return;
    int lane = idx & 63;
    int t = idx >> 6;            // (kk*4+nt)*2+ks
    int ks = t & 1;
    int nt = (t >> 1) & 3;
    int kk = t >> 3;
    const float* S = (kk < 16) ? (bond_W + kk * 4096) : bond_b;
    int quad = lane >> 4, col = lane & 15;
    short hi[8], lo[8];
#pragma unroll
    for (int j = 0; j < 8; ++j) {
        int i = ks * 32 + quad * 8 + j;
        float v = S[i * 64 + nt * 16 + col];
        short hb = f2bf(v);
        hi[j] = hb;
        lo[j] = f2bf(v - bf2f(hb));
    }
    short* dh = wf + (((size_t)(t * 2 + 0) * 64 + lane) * 8);
    short* dl = wf + (((size_t)(t * 2 + 1) * 64 + lane) * 8);
#pragma unroll
    for (int j = 0; j < 8; ++j) { dh[j] = hi[j]; dl[j] = lo[j]; }
}

// ---------------- message GEMM via split-bf16 MFMA + scatter-add ----------------
__launch_bounds__(256)
__global__ void k_msg2(const float* __restrict__ feat, const float* __restrict__ ef_t,
                       const short* __restrict__ wf,
                       const int* __restrict__ src, const int* __restrict__ dst,
                       float* __restrict__ agg) {
    __shared__ float efs[17 * 64];   // [kk][e_local]
    __shared__ int srcs[64];
    __shared__ int dsts[64];

    int tid = threadIdx.x;
    int e0 = blockIdx.x * 64;
    int lane = tid & 63;
    int nt = tid >> 6;
    int quad = lane >> 4, col = lane & 15;

    if (tid < 64) {
        int eg = e0 + tid;
        srcs[tid] = (eg < E) ? src[eg] : 0;
        dsts[tid] = (eg < E) ? dst[eg] : 0;
    }
    for (int i = tid; i < 17 * 64; i += 256) {
        int kk = i >> 6, e = i & 63;
        int eg = e0 + e;
        efs[i] = (eg < E) ? ef_t[kk * E + eg] : 0.0f;
    }
    __syncthreads();

    // A fragments (feat, split hi/lo), constant across kk
    short8 Ah[4][2], Al[4][2];
#pragma unroll
    for (int mt = 0; mt < 4; ++mt) {
        int s = srcs[mt * 16 + col];
        const float* fp = feat + (size_t)s * 64 + quad * 8;
#pragma unroll
        for (int ks = 0; ks < 2; ++ks) {
            float4 u0 = *(const float4*)(fp + ks * 32);
            float4 u1 = *(const float4*)(fp + ks * 32 + 4);
            float vv[8] = {u0.x, u0.y, u0.z, u0.w, u1.x, u1.y, u1.z, u1.w};
            short8 hi, lo;
#pragma unroll
            for (int j = 0; j < 8; ++j) {
                short hb = f2bf(vv[j]);
                hi[j] = hb;
                lo[j] = f2bf(vv[j] - bf2f(hb));
            }
            Ah[mt][ks] = hi;
            Al[mt][ks] = lo;
        }
    }

    const short8* Wf = (const short8*)wf;
    float C[4][4] = {};

    int tb = nt * 2;
    short8 Bh0 = Wf[((tb + 0) * 2 + 0) * 64 + lane];
    short8 Bh1 = Wf[((tb + 1) * 2 + 0) * 64 + lane];
    short8 Bl0 = Wf[((tb + 0) * 2 + 1) * 64 + lane];
    short8 Bl1 = Wf[((tb + 1) * 2 + 1) * 64 + lane];

#pragma unroll 1
    for (int kk = 0; kk < 17; ++kk) {
        int kn = (kk < 16) ? (kk + 1) : 16;
        int tn = (kn * 4 + nt) * 2;
        short8 nh0 = Wf[((tn + 0) * 2 + 0) * 64 + lane];
        short8 nh1 = Wf[((tn + 1) * 2 + 0) * 64 + lane];
        short8 nl0 = Wf[((tn + 0) * 2 + 1) * 64 + lane];
        short8 nl1 = Wf[((tn + 1) * 2 + 1) * 64 + lane];

#pragma unroll
        for (int mt = 0; mt < 4; ++mt) {
            floatx4 T = {0.0f, 0.0f, 0.0f, 0.0f};
            T = __builtin_amdgcn_mfma_f32_16x16x32_bf16(Ah[mt][0], Bh0, T, 0, 0, 0);
            T = __builtin_amdgcn_mfma_f32_16x16x32_bf16(Ah[mt][1], Bh1, T, 0, 0, 0);
            T = __builtin_amdgcn_mfma_f32_16x16x32_bf16(Al[mt][0], Bh0, T, 0, 0, 0);
            T = __builtin_amdgcn_mfma_f32_16x16x32_bf16(Al[mt][1], Bh1, T, 0, 0, 0);
            T = __builtin_amdgcn_mfma_f32_16x16x32_bf16(Ah[mt][0], Bl0, T, 0, 0, 0);
            T = __builtin_amdgcn_mfma_f32_16x16x32_bf16(Ah[mt][1], Bl1, T, 0, 0, 0);
            float4 ef = *(const float4*)&efs[kk * 64 + mt * 16 + quad * 4];
            C[mt][0] += ef.x * T[0];
            C[mt][1] += ef.y * T[1];
            C[mt][2] += ef.z * T[2];
            C[mt][3] += ef.w * T[3];
        }
        Bh0 = nh0; Bh1 = nh1; Bl0 = nl0; Bl1 = nl1;
    }

    int o = nt * 16 + col;
#pragma unroll
    for (int mt = 0; mt < 4; ++mt) {
#pragma unroll
        for (int r = 0; r < 4; ++r) {
            int e_l = mt * 16 + quad * 4 + r;
            if (e0 + e_l < E) {
                atomicAdd(agg + (size_t)dsts[e_l] * 64 + o, C[mt][r]);
            }
        }
    }
}

// ---------------- GRU step: h = GRU(relu(agg), h) ----------------
__launch_bounds__(256)
__global__ void k_gru(const float* __restrict__ agg, float* __restrict__ h,
                      const float* __restrict__ WihT, const float* __restrict__ WhhT,
                      const float* __restrict__ bih, const float* __restrict__ bhh) {
    __shared__ float gx_s[16 * 64];
    __shared__ float h_s[16 * 64];
    int tid = threadIdx.x;
    int n0 = blockIdx.x * 16;
    for (int i = tid; i < 16 * 64; i += 256) {
        int nn = i >> 6, ii = i & 63;
        int n = n0 + nn;
        float a = (n < N) ? agg[n * 64 + ii] : 0.0f;
        gx_s[i] = fmaxf(a, 0.0f);
        h_s[i] = (n < N) ? h[n * 64 + ii] : 0.0f;
    }
    __syncthreads();
    int o = tid & 63, ng = tid >> 6;
    float air[4] = {}, aiz[4] = {}, ain[4] = {}, ahr[4] = {}, ahz[4] = {}, ahn[4] = {};
#pragma unroll 4
    for (int i = 0; i < 64; ++i) {
        float wr = WihT[i * 192 + o], wz = WihT[i * 192 + 64 + o], wn = WihT[i * 192 + 128 + o];
        float ur = WhhT[i * 192 + o], uz = WhhT[i * 192 + 64 + o], un = WhhT[i * 192 + 128 + o];
#pragma unroll
        for (int j = 0; j < 4; ++j) {
            float gx = gx_s[(ng * 4 + j) * 64 + i];
            float hh = h_s[(ng * 4 + j) * 64 + i];
            air[j] += gx * wr; aiz[j] += gx * wz; ain[j] += gx * wn;
            ahr[j] += hh * ur; ahz[j] += hh * uz; ahn[j] += hh * un;
        }
    }
    float br = bih[o], bz = bih[64 + o], bn = bih[128 + o];
    float cr = bhh[o], cz = bhh[64 + o], cn = bhh[128 + o];
#pragma unroll
    for (int j = 0; j < 4; ++j) {
        int n = n0 + ng * 4 + j;
        if (n >= N) continue;
        float r = sigf(air[j] + br + ahr[j] + cr);
        float z = sigf(aiz[j] + bz + ahz[j] + cz);
        float nn_ = tanhf(ain[j] + bn + r * (ahn[j] + cn));
        float hold = h_s[(ng * 4 + j) * 64 + o];
        h[n * 64 + o] = (1.0f - z) * nn_ + z * hold;
    }
}

// ---------------- graph bounds ----------------
__global__ void k_binit(int* gs, int* ge) {
    int g = threadIdx.x;
    if (g < B) { gs[g] = N; ge[g] = 0; }
}
__global__ void k_bounds(const int* __restrict__ ng, int* gs, int* ge) {
    int n = blockIdx.x * 256 + threadIdx.x;
    if (n < N) {
        int g = ng[n];
        atomicMin(&gs[g], n);
        atomicMax(&ge[g], n + 1);
    }
}

// ---------------- Set2Set: 2-layer LSTM, one block per sample ----------------
__launch_bounds__(256)
__global__ void k_lstm(float* __restrict__ h0, float* __restrict__ c0,
                       float* __restrict__ h1, float* __restrict__ c1,
                       float* __restrict__ q_star,
                       const float* __restrict__ W0T, const float* __restrict__ U0T,
                       const float* __restrict__ b0i, const float* __restrict__ b0h,
                       const float* __restrict__ W1T, const float* __restrict__ U1T,
                       const float* __restrict__ b1i, const float* __restrict__ b1h,
                       unsigned* __restrict__ emax) {
    __shared__ float xb[256], hb[128], gb[512], h0n[128];
    int s = blockIdx.x, tid = threadIdx.x;
    if (tid == 0) emax[s] = fenc(-INFINITY);
    xb[tid] = q_star[s * 256 + tid];
    if (tid < 128) hb[tid] = h0[s * 128 + tid];
    __syncthreads();
    float g0 = b0i[tid] + b0h[tid];
    float g1 = b0i[tid + 256] + b0h[tid + 256];
    for (int i = 0; i < 256; ++i) {
        float x = xb[i];
        g0 += x * W0T[i * 512 + tid];
        g1 += x * W0T[i * 512 + tid + 256];
    }
    for (int i = 0; i < 128; ++i) {
        float hh = hb[i];
        g0 += hh * U0T[i * 512 + tid];
        g1 += hh * U0T[i * 512 + tid + 256];
    }
    gb[tid] = g0; gb[tid + 256] = g1;
    __syncthreads();
    if (tid < 128) {
        float ii = gb[tid], ff = gb[128 + tid], gg = gb[256 + tid], oo = gb[384 + tid];
        float c = sigf(ff) * c0[s * 128 + tid] + sigf(ii) * tanhf(gg);
        float hn = sigf(oo) * tanhf(c);
        c0[s * 128 + tid] = c; h0[s * 128 + tid] = hn; h0n[tid] = hn;
        hb[tid] = h1[s * 128 + tid];
    }
    __syncthreads();
    float ga = b1i[tid] + b1h[tid];
    float gbv = b1i[tid + 256] + b1h[tid + 256];
    for (int i = 0; i < 128; ++i) {
        float x = h0n[i], hh = hb[i];
        ga  += x * W1T[i * 512 + tid]       + hh * U1T[i * 512 + tid];
        gbv += x * W1T[i * 512 + tid + 256] + hh * U1T[i * 512 + tid + 256];
    }
    gb[tid] = ga; gb[tid + 256] = gbv;
    __syncthreads();
    if (tid < 128) {
        float ii = gb[tid], ff = gb[128 + tid], gg = gb[256 + tid], oo = gb[384 + tid];
        float c = sigf(ff) * c1[s * 128 + tid] + sigf(ii) * tanhf(gg);
        float hn = sigf(oo) * tanhf(c);
        c1[s * 128 + tid] = c; h1[s * 128 + tid] = hn;
        q_star[s * 256 + tid] = hn;
        q_star[s * 256 + 128 + tid] = 0.f;
    }
}

// ---------------- attention: e[n] = dot([h|x][n], q[g]); block = 64 nodes, LDS tile ----------------
__launch_bounds__(256)
__global__ void k_e2(const float* __restrict__ h, const float* __restrict__ x,
                     const float* __restrict__ q, const int* __restrict__ ngr,
                     float* __restrict__ e_out, unsigned* __restrict__ emax) {
    __shared__ float nas[128 * 66];   // [d][node], stride 66 (2-way bank alias = free)
    __shared__ float red[256];
    __shared__ int gl[64];
    __shared__ float el[64];
    int tid = threadIdx.x;
    int n0 = blockIdx.x * 64;
    for (int i = tid; i < 64 * 64; i += 256) {
        int node = i >> 6, d = i & 63;
        int n = n0 + node;
        float hv = (n < N) ? h[(size_t)n * 64 + d] : 0.0f;
        float xv = (n < N) ? x[(size_t)n * 64 + d] : 0.0f;
        nas[d * 66 + node] = hv;
        nas[(64 + d) * 66 + node] = xv;
    }
    if (tid < 64) {
        int n = n0 + tid;
        gl[tid] = (n < N) ? ngr[n] : -1;
    }
    __syncthreads();
    int node_l = tid & 63, part = tid >> 6;
    int g = gl[node_l];
    const float* qp = q + (size_t)((g < 0) ? 0 : g) * 128 + part * 32;
    float acc = 0.0f;
#pragma unroll 8
    for (int j = 0; j < 32; ++j)
        acc += nas[(part * 32 + j) * 66 + node_l] * qp[j];
    red[tid] = acc;
    __syncthreads();
    if (tid < 64) {
        float e = red[tid] + red[tid + 64] + red[tid + 128] + red[tid + 192];
        el[tid] = e;
        if (n0 + tid < N) e_out[n0 + tid] = e;
    }
    __syncthreads();
    if (tid < 64) {
        int gg = gl[tid];
        if (gg >= 0 && (tid == 0 || gl[tid - 1] != gg)) {
            float m = el[tid];
            for (int j = tid + 1; j < 64 && gl[j] == gg; ++j) m = fmaxf(m, el[j]);
            atomicMax(&emax[gg], fenc(m));
        }
    }
}

// ---------------- fused softmax-denominator + weighted pooling (per graph) ----------------
// r_out[g][d] = (sum_n exp(e[n]-m) * na[n][d]) / (sum_n exp(e[n]-m))
__launch_bounds__(256)
__global__ void k_r2(const float* __restrict__ h, const float* __restrict__ x,
                     const float* __restrict__ e_buf, const unsigned* __restrict__ emax,
                     const int* __restrict__ gs, const int* __restrict__ ge,
                     float* __restrict__ q_star) {
    __shared__ float exs[256];
    __shared__ float red[256];
    int g = blockIdx.x, tid = threadIdx.x;
    int s0 = gs[g], s1 = ge[g];
    if (s1 <= s0) {
        if (tid < 128) q_star[g * 256 + 128 + tid] = 0.0f;
        return;
    }
    float m = fdec(emax[g]);
    int d = tid & 127, c = tid >> 7;
    float acc = 0.0f, den_acc = 0.0f;
    for (int base = s0; base < s1; base += 256) {
        int n = base + tid;
        float ex = (n < s1) ? expf(e_buf[n] - m) : 0.0f;
        __syncthreads();
        exs[tid] = ex;
        den_acc += ex;
        __syncthreads();
        int lim = min(256, s1 - base);
        for (int j = c; j < lim; j += 2) {
            int n2 = base + j;
            float na = (d < 64) ? h[(size_t)n2 * 64 + d] : x[(size_t)n2 * 64 + (d - 64)];
            acc += na * exs[j];
        }
    }
    red[tid] = den_acc;
    __syncthreads();
    for (int s = 128; s > 0; s >>= 1) {
        if (tid < s) red[tid] += red[tid + s];
        __syncthreads();
    }
    float den = red[0];
    __syncthreads();
    red[tid] = acc;
    __syncthreads();
    if (tid < 128)
        q_star[g * 256 + 128 + tid] = (red[tid] + red[tid + 128]) / den;
}

// ---------------- head: sparsify + MLP + softmax, one block per sample ----------------
__launch_bounds__(256)
__global__ void k_head(const float* __restrict__ q_star,
                       const float* __restrict__ spW, const float* __restrict__ spb,
                       const float* __restrict__ pa,
                       const float* __restrict__ W1, const float* __restrict__ b1,
                       const float* __restrict__ W2, const float* __restrict__ b2,
                       const float* __restrict__ oW, const float* __restrict__ ob,
                       float* __restrict__ out) {
    __shared__ float row[256], buf0[512], buf1[512];
    int s = blockIdx.x, tid = threadIdx.x;
    row[tid] = q_star[s * 256 + tid];
    __syncthreads();
    float a = pa[0];
    float f0 = spb[tid], f1 = spb[tid + 256];
    for (int i = 0; i < 256; ++i) {
        float q = row[i];
        f0 += q * spW[i * 512 + tid];
        f1 += q * spW[i * 512 + tid + 256];
    }
    buf0[tid] = (f0 >= 0.0f) ? f0 : a * f0;
    buf0[tid + 256] = (f1 >= 0.0f) ? f1 : a * f1;
    __syncthreads();
    float g0 = b1[tid], g1 = b1[tid + 256];
    for (int i = 0; i < 512; ++i) {
        float v = buf0[i];
        g0 += v * W1[i * 512 + tid];
        g1 += v * W1[i * 512 + tid + 256];
    }
    buf1[tid] = fmaxf(g0, 0.0f);
    buf1[tid + 256] = fmaxf(g1, 0.0f);
    __syncthreads();
    float t0 = b2[tid], t1 = b2[tid + 256];
    for (int i = 0; i < 512; ++i) {
        float v = buf1[i];
        t0 += v * W2[i * 512 + tid];
        t1 += v * W2[i * 512 + tid + 256];
    }
    buf0[tid] = tanhf(t0);
    buf0[tid + 256] = tanhf(t1);
    __syncthreads();
    if (tid < 64) {
        float v = -INFINITY;
        if (tid < 54) {
            v = ob[tid];
            for (int i = 0; i < 512; ++i) v += buf0[i] * oW[i * 54 + tid];
        }
        float m = v;
#pragma unroll
        for (int off = 32; off; off >>= 1) m = fmaxf(m, __shfl_xor(m, off, 64));
        float ex = (tid < 54) ? expf(v - m) : 0.0f;
        float ssum = ex;
#pragma unroll
        for (int off = 32; off; off >>= 1) ssum += __shfl_xor(ssum, off, 64);
        if (tid < 54) out[s * 54 + tid] = ex / ssum;
    }
}

// ---------------- driver ----------------
extern "C" void kernel_launch(void* const* d_in, const int* in_sizes, int n_in,
                              void* d_out, int out_size, void* d_ws, size_t ws_size,
                              hipStream_t stream) {
    const float* node_attr = (const float*)d_in[0];
    const float* edge_attr = (const float*)d_in[1];
    const float* edge_len  = (const float*)d_in[2];
    const int*   src       = (const int*)d_in[3];
    const int*   dst       = (const int*)d_in[4];
    const int*   node_grph = (const int*)d_in[5];
    const float* proj_W    = (const float*)d_in[6];
    const float* proj_b    = (const float*)d_in[7];
    const float* centers   = (const float*)d_in[8];
    const float* beta      = (const float*)d_in[9];
    const float* bond_W    = (const float*)d_in[10];
    const float* bond_b    = (const float*)d_in[11];
    const float* conv_b    = (const float*)d_in[12];
    const float* gru_Wih   = (const float*)d_in[13];
    const float* gru_Whh   = (const float*)d_in[14];
    const float* gru_bih   = (const float*)d_in[15];
    const float* gru_bhh   = (const float*)d_in[16];
    const float* lWih0     = (const float*)d_in[17];
    const float* lWhh0     = (const float*)d_in[18];
    const float* lbih0     = (const float*)d_in[19];
    const float* lbhh0     = (const float*)d_in[20];
    const float* lWih1     = (const float*)d_in[21];
    const float* lWhh1     = (const float*)d_in[22];
    const float* lbih1     = (const float*)d_in[23];
    const float* lbhh1     = (const float*)d_in[24];
    const float* sp_W      = (const float*)d_in[25];
    const float* sp_b      = (const float*)d_in[26];
    const float* prelu_a   = (const float*)d_in[27];
    const float* h0_W1     = (const float*)d_in[28];
    const float* h0_b1     = (const float*)d_in[29];
    const float* h0_W2     = (const float*)d_in[30];
    const float* h0_b2     = (const float*)d_in[31];
    const float* out_W     = (const float*)d_in[32];
    const float* out_b     = (const float*)d_in[33];
    float* out = (float*)d_out;

    float* ws = (float*)d_ws;
    size_t off = 0;
    float* x      = ws + off; off += (size_t)N * 64;
    float* h      = ws + off; off += (size_t)N * 64;
    float* ef_t   = ws + off; off += (size_t)E * 17;
    float* agg    = ws + off; off += (size_t)N * 64;
    float* wfrag  = ws + off; off += 17 * 16 * 64 * 8 / 2;
    float* gWihT  = ws + off; off += 64 * 192;
    float* gWhhT  = ws + off; off += 64 * 192;
    float* lW0T   = ws + off; off += 256 * 512;
    float* lU0T   = ws + off; off += 128 * 512;
    float* lW1T   = ws + off; off += 128 * 512;
    float* lU1T   = ws + off; off += 128 * 512;
    float* h0     = ws + off; off += B * 128;
    float* c0     = ws + off; off += B * 128;
    float* h1     = ws + off; off += B * 128;
    float* c1     = ws + off; off += B * 128;
    float* q_star = ws + off; off += B * 256;
    float* e_buf  = ws + off; off += N;
    unsigned* emax = (unsigned*)(ws + off); off += B;
    int* gs       = (int*)(ws + off); off += B;
    int* ge       = (int*)(ws + off); off += B;

    k_transpose<<<(192 * 64 + 255) / 256, 256, 0, stream>>>(gru_Wih, gWihT, 192, 64);
    k_transpose<<<(192 * 64 + 255) / 256, 256, 0, stream>>>(gru_Whh, gWhhT, 192, 64);
    k_transpose<<<(512 * 256 + 255) / 256, 256, 0, stream>>>(lWih0, lW0T, 512, 256);
    k_transpose<<<(512 * 128 + 255) / 256, 256, 0, stream>>>(lWhh0, lU0T, 512, 128);
    k_transpose<<<(512 * 128 + 255) / 256, 256, 0, stream>>>(lWhh1, lU1T, 512, 128);
    k_transpose<<<(512 * 128 + 255) / 256, 256, 0, stream>>>(lWih1, lW1T, 512, 128);

    k_prepW<<<(17 * 4 * 2 * 64 + 255) / 256, 256, 0, stream>>>(bond_W, bond_b, (short*)wfrag);

    // zero LSTM state + q_star (contiguous region: h0,c0,h1,c1,q_star)
    k_fill<<<(4 * B * 128 + B * 256 + 255) / 256, 256, 0, stream>>>(h0, 0.0f, 4 * B * 128 + B * 256);

    k_proj<<<N / 16, 256, 0, stream>>>(node_attr, proj_W, proj_b, x, h);
    k_efeat<<<(E + 255) / 256, 256, 0, stream>>>(edge_attr, edge_len, centers, beta, ef_t);

    k_binit<<<1, 256, 0, stream>>>(gs, ge);
    k_bounds<<<(N + 255) / 256, 256, 0, stream>>>(node_grph, gs, ge);

    for (int step = 0; step < 4; ++step) {
        k_agginit<<<(N * 64 + 255) / 256, 256, 0, stream>>>(agg, conv_b);
        k_msg2<<<(E + 63) / 64, 256, 0, stream>>>(h, ef_t, (const short*)wfrag, src, dst, agg);
        k_gru<<<(N + 15) / 16, 256, 0, stream>>>(agg, h, gWihT, gWhhT, gru_bih, gru_bhh);
    }

    for (int it = 0; it < 3; ++it) {
        k_lstm<<<B, 256, 0, stream>>>(h0, c0, h1, c1, q_star,
                                      lW0T, lU0T, lbih0, lbhh0,
                                      lW1T, lU1T, lbih1, lbhh1, emax);
        k_e2<<<(N + 63) / 64, 256, 0, stream>>>(h, x, h1, node_grph, e_buf, emax);
        k_r2<<<B, 256, 0, stream>>>(h, x, e_buf, emax, gs, ge, q_star);
    }

    k_head<<<B, 256, 0, stream>>>(q_star, sp_W, sp_b, prelu_a,
                                  h0_W1, h0_b1, h0_W2, h0_b2, out_W, out_b, out);
}

// Round 4
// 961.686 us; speedup vs baseline: 2.5146x; 1.2188x over previous
//
#include <hip/hip_runtime.h>
#include <math.h>

constexpr int N = 50000;     // nodes
constexpr int E = 100000;    // edges
constexpr int B = 256;       // graphs
constexpr int H = 64;
constexpr int DN = 110;

#define DEV __device__ __forceinline__

typedef __attribute__((ext_vector_type(8))) short short8;
typedef __attribute__((ext_vector_type(4))) float floatx4;

DEV float sigf(float x) { return 1.0f / (1.0f + expf(-x)); }

DEV unsigned fenc(float x) {
    unsigned u = __float_as_uint(x);
    return (u & 0x80000000u) ? ~u : (u | 0x80000000u);
}
DEV float fdec(unsigned u) {
    return (u & 0x80000000u) ? __uint_as_float(u & 0x7fffffffu) : __uint_as_float(~u);
}

// bf16 round-to-nearest-even conversion (manual, header-type-free)
DEV short f2bf(float f) {
    unsigned u = __float_as_uint(f);
    unsigned r = (u + 0x7fffu + ((u >> 16) & 1u)) >> 16;
    return (short)r;
}
DEV float bf2f(short s) { return __uint_as_float(((unsigned)(unsigned short)s) << 16); }

// convert 8 contiguous floats -> hi/lo bf16 fragments
DEV void cvt8(const float* p, short8& hi, short8& lo) {
    float4 u0 = *(const float4*)p;
    float4 u1 = *(const float4*)(p + 4);
    float vv[8] = {u0.x, u0.y, u0.z, u0.w, u1.x, u1.y, u1.z, u1.w};
#pragma unroll
    for (int j = 0; j < 8; ++j) {
        short hb = f2bf(vv[j]);
        hi[j] = hb;
        lo[j] = f2bf(vv[j] - bf2f(hb));
    }
}

// ---------------- generic helpers ----------------
__global__ void k_fill(float* p, float v, int n) {
    int i = blockIdx.x * 256 + threadIdx.x;
    if (i < n) p[i] = v;
}

// out[c*R + r] = in[r*C + c]   (in is R x C)
__global__ void k_transpose(const float* in, float* out, int R, int C) {
    int idx = blockIdx.x * 256 + threadIdx.x;
    if (idx < R * C) {
        int r = idx / C, c = idx % C;
        out[c * R + r] = in[idx];
    }
}

// ---------------- generic B-fragment prep (split bf16 hi/lo) ----------------
// Produces frags for D = A(MxK) @ W(KxNout): lane holds B[k=kt*32+quad*8+j][o=ntile*16+col].
// slot t = kt*NT16 + ntile; short8 index (t*2+part)*64 + lane  (part 0=hi, 1=lo)
// trans==0: W[k*ld + o]  (in-major);  trans==1: W[o*ld + k]  (out-major / PyTorch)
__global__ void k_prepB(const float* __restrict__ W, short* __restrict__ out,
                        int NT16, int ld, int trans, int ocap, int total) {
    int idx = blockIdx.x * 256 + threadIdx.x;
    if (idx >= total) return;
    int lane = idx & 63;
    int t = idx >> 6;
    int ntile = t % NT16;
    int kt = t / NT16;
    int quad = lane >> 4, col = lane & 15;
    int o = ntile * 16 + col;
    short hi[8], lo[8];
#pragma unroll
    for (int j = 0; j < 8; ++j) {
        int k = kt * 32 + quad * 8 + j;
        float v = 0.0f;
        if (o < ocap) v = trans ? W[(size_t)o * ld + k] : W[(size_t)k * ld + o];
        short hb = f2bf(v);
        hi[j] = hb;
        lo[j] = f2bf(v - bf2f(hb));
    }
    short* dh = out + (((size_t)(t * 2 + 0) * 64 + lane) * 8);
    short* dl = out + (((size_t)(t * 2 + 1) * 64 + lane) * 8);
#pragma unroll
    for (int j = 0; j < 8; ++j) { dh[j] = hi[j]; dl[j] = lo[j]; }
}

// ---------------- projection: x = relu(na @ W + b); h = x ----------------
__launch_bounds__(256)
__global__ void k_proj(const float* __restrict__ na, const float* __restrict__ W,
                       const float* __restrict__ b, float* __restrict__ x, float* __restrict__ h) {
    __shared__ float Ws[DN * 64];
    __shared__ float as[16][112];
    int tid = threadIdx.x;
    for (int i = tid; i < DN * 64; i += 256) Ws[i] = W[i];
    int n0 = blockIdx.x * 16;
    for (int i = tid; i < 16 * DN; i += 256) {
        int nn = i / DN, ii = i % DN;
        as[nn][ii] = na[(n0 + nn) * DN + ii];
    }
    __syncthreads();
    int o = tid & 63, ng = tid >> 6;
    float bo = b[o];
    for (int j = 0; j < 4; ++j) {
        int nn = ng * 4 + j;
        float acc = bo;
#pragma unroll 10
        for (int i = 0; i < DN; ++i) acc += as[nn][i] * Ws[i * 64 + o];
        float v = fmaxf(acc, 0.0f);
        int n = n0 + nn;
        x[n * 64 + o] = v;
        h[n * 64 + o] = v;
    }
}

// ---------------- edge features -> transposed layout ef_t[kk][e], kk 0..16 ----------------
__global__ void k_efeat(const float* __restrict__ ea, const float* __restrict__ el,
                        const float* __restrict__ centers, const float* __restrict__ beta,
                        float* __restrict__ ef_t) {
    int e = blockIdx.x * 256 + threadIdx.x;
    if (e >= E) return;
    float L = el[e];
#pragma unroll
    for (int j = 0; j < 8; ++j) ef_t[j * E + e] = ea[e * 8 + j];
#pragma unroll
    for (int j = 0; j < 8; ++j) {
        float d = L - centers[j];
        ef_t[(8 + j) * E + e] = expf(-beta[j] * d * d);
    }
    ef_t[16 * E + e] = 1.0f;
}

// ---------------- agg init with conv bias ----------------
__global__ void k_agginit(float* __restrict__ agg, const float* __restrict__ conv_b) {
    int idx = blockIdx.x * 256 + threadIdx.x;
    if (idx < N * 64) agg[idx] = conv_b[idx & 63];
}

// ---------------- precompute bond_W (+bond_b as kk=16) into MFMA B-fragment layout ----------------
__global__ void k_prepW(const float* __restrict__ bond_W, const float* __restrict__ bond_b,
                        short* __restrict__ wf) {
    int idx = blockIdx.x * 256 + threadIdx.x;
    if (idx >= 17 * 4 * 2 * 64) return;
    int lane = idx & 63;
    int t = idx >> 6;            // (kk*4+nt)*2+ks
    int ks = t & 1;
    int nt = (t >> 1) & 3;
    int kk = t >> 3;
    const float* S = (kk < 16) ? (bond_W + kk * 4096) : bond_b;
    int quad = lane >> 4, col = lane & 15;
    short hi[8], lo[8];
#pragma unroll
    for (int j = 0; j < 8; ++j) {
        int i = ks * 32 + quad * 8 + j;
        float v = S[i * 64 + nt * 16 + col];
        short hb = f2bf(v);
        hi[j] = hb;
        lo[j] = f2bf(v - bf2f(hb));
    }
    short* dh = wf + (((size_t)(t * 2 + 0) * 64 + lane) * 8);
    short* dl = wf + (((size_t)(t * 2 + 1) * 64 + lane) * 8);
#pragma unroll
    for (int j = 0; j < 8; ++j) { dh[j] = hi[j]; dl[j] = lo[j]; }
}

// ---------------- message GEMM via split-bf16 MFMA + scatter-add ----------------
__launch_bounds__(256)
__global__ void k_msg2(const float* __restrict__ feat, const float* __restrict__ ef_t,
                       const short* __restrict__ wf,
                       const int* __restrict__ src, const int* __restrict__ dst,
                       float* __restrict__ agg) {
    __shared__ float efs[17 * 64];   // [kk][e_local]
    __shared__ int srcs[64];
    __shared__ int dsts[64];

    int tid = threadIdx.x;
    int e0 = blockIdx.x * 64;
    int lane = tid & 63;
    int nt = tid >> 6;
    int quad = lane >> 4, col = lane & 15;

    if (tid < 64) {
        int eg = e0 + tid;
        srcs[tid] = (eg < E) ? src[eg] : 0;
        dsts[tid] = (eg < E) ? dst[eg] : 0;
    }
    for (int i = tid; i < 17 * 64; i += 256) {
        int kk = i >> 6, e = i & 63;
        int eg = e0 + e;
        efs[i] = (eg < E) ? ef_t[kk * E + eg] : 0.0f;
    }
    __syncthreads();

    // A fragments (feat, split hi/lo), constant across kk
    short8 Ah[4][2], Al[4][2];
#pragma unroll
    for (int mt = 0; mt < 4; ++mt) {
        int s = srcs[mt * 16 + col];
        const float* fp = feat + (size_t)s * 64 + quad * 8;
#pragma unroll
        for (int ks = 0; ks < 2; ++ks) cvt8(fp + ks * 32, Ah[mt][ks], Al[mt][ks]);
    }

    const short8* Wf = (const short8*)wf;
    float C[4][4] = {};

    int tb = nt * 2;
    short8 Bh0 = Wf[((tb + 0) * 2 + 0) * 64 + lane];
    short8 Bh1 = Wf[((tb + 1) * 2 + 0) * 64 + lane];
    short8 Bl0 = Wf[((tb + 0) * 2 + 1) * 64 + lane];
    short8 Bl1 = Wf[((tb + 1) * 2 + 1) * 64 + lane];

#pragma unroll 1
    for (int kk = 0; kk < 17; ++kk) {
        int kn = (kk < 16) ? (kk + 1) : 16;
        int tn = (kn * 4 + nt) * 2;
        short8 nh0 = Wf[((tn + 0) * 2 + 0) * 64 + lane];
        short8 nh1 = Wf[((tn + 1) * 2 + 0) * 64 + lane];
        short8 nl0 = Wf[((tn + 0) * 2 + 1) * 64 + lane];
        short8 nl1 = Wf[((tn + 1) * 2 + 1) * 64 + lane];

#pragma unroll
        for (int mt = 0; mt < 4; ++mt) {
            floatx4 T = {0.0f, 0.0f, 0.0f, 0.0f};
            T = __builtin_amdgcn_mfma_f32_16x16x32_bf16(Ah[mt][0], Bh0, T, 0, 0, 0);
            T = __builtin_amdgcn_mfma_f32_16x16x32_bf16(Ah[mt][1], Bh1, T, 0, 0, 0);
            T = __builtin_amdgcn_mfma_f32_16x16x32_bf16(Al[mt][0], Bh0, T, 0, 0, 0);
            T = __builtin_amdgcn_mfma_f32_16x16x32_bf16(Al[mt][1], Bh1, T, 0, 0, 0);
            T = __builtin_amdgcn_mfma_f32_16x16x32_bf16(Ah[mt][0], Bl0, T, 0, 0, 0);
            T = __builtin_amdgcn_mfma_f32_16x16x32_bf16(Ah[mt][1], Bl1, T, 0, 0, 0);
            float4 ef = *(const float4*)&efs[kk * 64 + mt * 16 + quad * 4];
            C[mt][0] += ef.x * T[0];
            C[mt][1] += ef.y * T[1];
            C[mt][2] += ef.z * T[2];
            C[mt][3] += ef.w * T[3];
        }
        Bh0 = nh0; Bh1 = nh1; Bl0 = nl0; Bl1 = nl1;
    }

    int o = nt * 16 + col;
#pragma unroll
    for (int mt = 0; mt < 4; ++mt) {
#pragma unroll
        for (int r = 0; r < 4; ++r) {
            int e_l = mt * 16 + quad * 4 + r;
            if (e0 + e_l < E) {
                atomicAdd(agg + (size_t)dsts[e_l] * 64 + o, C[mt][r]);
            }
        }
    }
}

// ---------------- GRU step via split-bf16 MFMA: h = GRU(relu(agg), h) ----------------
// Block = 32 nodes (2 m-tiles), 4 waves; wave nt covers o-slice nt*16..+15 for ALL 6 gate matrices.
// gi = gx @ Wih^T (64x192), gh = h @ Whh^T; fragments precomputed (trans=1).
__launch_bounds__(256)
__global__ void k_gru2(const float* __restrict__ agg, float* __restrict__ h,
                       const short* __restrict__ fI, const short* __restrict__ fH,
                       const float* __restrict__ bih, const float* __restrict__ bhh) {
    int tid = threadIdx.x, lane = tid & 63, nt = tid >> 6;
    int quad = lane >> 4, col = lane & 15;
    int n0 = blockIdx.x * 32;

    // A fragments: gx = relu(agg[node]), hh = h[node]; node = n0 + mt*16 + col
    short8 Gh[2][2], Gl[2][2], Hh[2][2], Hl[2][2];
#pragma unroll
    for (int mt = 0; mt < 2; ++mt) {
        int node = n0 + mt * 16 + col;
        bool ok = node < N;
        size_t base = (size_t)(ok ? node : 0) * 64 + quad * 8;
#pragma unroll
        for (int ks = 0; ks < 2; ++ks) {
            float4 a0 = *(const float4*)(agg + base + ks * 32);
            float4 a1 = *(const float4*)(agg + base + ks * 32 + 4);
            float4 h0 = *(const float4*)(h + base + ks * 32);
            float4 h1 = *(const float4*)(h + base + ks * 32 + 4);
            float gv[8] = {a0.x, a0.y, a0.z, a0.w, a1.x, a1.y, a1.z, a1.w};
            float hv[8] = {h0.x, h0.y, h0.z, h0.w, h1.x, h1.y, h1.z, h1.w};
#pragma unroll
            for (int j = 0; j < 8; ++j) {
                float g = ok ? fmaxf(gv[j], 0.0f) : 0.0f;
                float hh = ok ? hv[j] : 0.0f;
                short gb = f2bf(g);
                Gh[mt][ks][j] = gb;
                Gl[mt][ks][j] = f2bf(g - bf2f(gb));
                short hb = f2bf(hh);
                Hh[mt][ks][j] = hb;
                Hl[mt][ks][j] = f2bf(hh - bf2f(hb));
            }
        }
    }
    __syncthreads();  // all h reads complete before any wave writes h below

    const short8* FI = (const short8*)fI;
    const short8* FH = (const short8*)fH;
    floatx4 aI[2][3] = {}, aH[2][3] = {};
#pragma unroll
    for (int ks = 0; ks < 2; ++ks) {
        short8 bIh[3], bIl[3], bHh[3], bHl[3];
#pragma unroll
        for (int g = 0; g < 3; ++g) {
            int t = ks * 12 + g * 4 + nt;   // NT16 = 12 (Nout=192)
            bIh[g] = FI[(t * 2 + 0) * 64 + lane];
            bIl[g] = FI[(t * 2 + 1) * 64 + lane];
            bHh[g] = FH[(t * 2 + 0) * 64 + lane];
            bHl[g] = FH[(t * 2 + 1) * 64 + lane];
        }
#pragma unroll
        for (int mt = 0; mt < 2; ++mt) {
#pragma unroll
            for (int g = 0; g < 3; ++g) {
                aI[mt][g] = __builtin_amdgcn_mfma_f32_16x16x32_bf16(Gh[mt][ks], bIh[g], aI[mt][g], 0, 0, 0);
                aI[mt][g] = __builtin_amdgcn_mfma_f32_16x16x32_bf16(Gl[mt][ks], bIh[g], aI[mt][g], 0, 0, 0);
                aI[mt][g] = __builtin_amdgcn_mfma_f32_16x16x32_bf16(Gh[mt][ks], bIl[g], aI[mt][g], 0, 0, 0);
                aH[mt][g] = __builtin_amdgcn_mfma_f32_16x16x32_bf16(Hh[mt][ks], bHh[g], aH[mt][g], 0, 0, 0);
                aH[mt][g] = __builtin_amdgcn_mfma_f32_16x16x32_bf16(Hl[mt][ks], bHh[g], aH[mt][g], 0, 0, 0);
                aH[mt][g] = __builtin_amdgcn_mfma_f32_16x16x32_bf16(Hh[mt][ks], bHl[g], aH[mt][g], 0, 0, 0);
            }
        }
    }

    int o = nt * 16 + col;
    float br = bih[o], bz = bih[64 + o], bn = bih[128 + o];
    float cr = bhh[o], cz = bhh[64 + o], cn = bhh[128 + o];
#pragma unroll
    for (int mt = 0; mt < 2; ++mt) {
#pragma unroll
        for (int r = 0; r < 4; ++r) {
            int node = n0 + mt * 16 + quad * 4 + r;
            if (node >= N) continue;
            float rg = sigf(aI[mt][0][r] + br + aH[mt][0][r] + cr);
            float z  = sigf(aI[mt][1][r] + bz + aH[mt][1][r] + cz);
            float ng = tanhf(aI[mt][2][r] + bn + rg * (aH[mt][2][r] + cn));
            float hold = h[(size_t)node * 64 + o];
            h[(size_t)node * 64 + o] = (1.0f - z) * ng + z * hold;
        }
    }
}

// ---------------- graph bounds ----------------
__global__ void k_binit(int* gs, int* ge) {
    int g = threadIdx.x;
    if (g < B) { gs[g] = N; ge[g] = 0; }
}
__global__ void k_bounds(const int* __restrict__ ng, int* gs, int* ge) {
    int n = blockIdx.x * 256 + threadIdx.x;
    if (n < N) {
        int g = ng[n];
        atomicMin(&gs[g], n);
        atomicMax(&ge[g], n + 1);
    }
}

// ---------------- Set2Set: 2-layer LSTM, one block per sample ----------------
__launch_bounds__(256)
__global__ void k_lstm(float* __restrict__ h0, float* __restrict__ c0,
                       float* __restrict__ h1, float* __restrict__ c1,
                       float* __restrict__ q_star,
                       const float* __restrict__ W0T, const float* __restrict__ U0T,
                       const float* __restrict__ b0i, const float* __restrict__ b0h,
                       const float* __restrict__ W1T, const float* __restrict__ U1T,
                       const float* __restrict__ b1i, const float* __restrict__ b1h,
                       unsigned* __restrict__ emax) {
    __shared__ float xb[256], hb[128], gb[512], h0n[128];
    int s = blockIdx.x, tid = threadIdx.x;
    if (tid == 0) emax[s] = fenc(-INFINITY);
    xb[tid] = q_star[s * 256 + tid];
    if (tid < 128) hb[tid] = h0[s * 128 + tid];
    __syncthreads();
    float g0 = b0i[tid] + b0h[tid];
    float g1 = b0i[tid + 256] + b0h[tid + 256];
    for (int i = 0; i < 256; ++i) {
        float x = xb[i];
        g0 += x * W0T[i * 512 + tid];
        g1 += x * W0T[i * 512 + tid + 256];
    }
    for (int i = 0; i < 128; ++i) {
        float hh = hb[i];
        g0 += hh * U0T[i * 512 + tid];
        g1 += hh * U0T[i * 512 + tid + 256];
    }
    gb[tid] = g0; gb[tid + 256] = g1;
    __syncthreads();
    if (tid < 128) {
        float ii = gb[tid], ff = gb[128 + tid], gg = gb[256 + tid], oo = gb[384 + tid];
        float c = sigf(ff) * c0[s * 128 + tid] + sigf(ii) * tanhf(gg);
        float hn = sigf(oo) * tanhf(c);
        c0[s * 128 + tid] = c; h0[s * 128 + tid] = hn; h0n[tid] = hn;
        hb[tid] = h1[s * 128 + tid];
    }
    __syncthreads();
    float ga = b1i[tid] + b1h[tid];
    float gbv = b1i[tid + 256] + b1h[tid + 256];
    for (int i = 0; i < 128; ++i) {
        float x = h0n[i], hh = hb[i];
        ga  += x * W1T[i * 512 + tid]       + hh * U1T[i * 512 + tid];
        gbv += x * W1T[i * 512 + tid + 256] + hh * U1T[i * 512 + tid + 256];
    }
    gb[tid] = ga; gb[tid + 256] = gbv;
    __syncthreads();
    if (tid < 128) {
        float ii = gb[tid], ff = gb[128 + tid], gg = gb[256 + tid], oo = gb[384 + tid];
        float c = sigf(ff) * c1[s * 128 + tid] + sigf(ii) * tanhf(gg);
        float hn = sigf(oo) * tanhf(c);
        c1[s * 128 + tid] = c; h1[s * 128 + tid] = hn;
        q_star[s * 256 + tid] = hn;
        q_star[s * 256 + 128 + tid] = 0.f;
    }
}

// ---------------- attention: e[n] = dot([h|x][n], q[g]); block = 64 nodes, LDS tile ----------------
__launch_bounds__(256)
__global__ void k_e2(const float* __restrict__ h, const float* __restrict__ x,
                     const float* __restrict__ q, const int* __restrict__ ngr,
                     float* __restrict__ e_out, unsigned* __restrict__ emax) {
    __shared__ float nas[128 * 66];
    __shared__ float red[256];
    __shared__ int gl[64];
    __shared__ float el[64];
    int tid = threadIdx.x;
    int n0 = blockIdx.x * 64;
    for (int i = tid; i < 64 * 64; i += 256) {
        int node = i >> 6, d = i & 63;
        int n = n0 + node;
        float hv = (n < N) ? h[(size_t)n * 64 + d] : 0.0f;
        float xv = (n < N) ? x[(size_t)n * 64 + d] : 0.0f;
        nas[d * 66 + node] = hv;
        nas[(64 + d) * 66 + node] = xv;
    }
    if (tid < 64) {
        int n = n0 + tid;
        gl[tid] = (n < N) ? ngr[n] : -1;
    }
    __syncthreads();
    int node_l = tid & 63, part = tid >> 6;
    int g = gl[node_l];
    const float* qp = q + (size_t)((g < 0) ? 0 : g) * 128 + part * 32;
    float acc = 0.0f;
#pragma unroll 8
    for (int j = 0; j < 32; ++j)
        acc += nas[(part * 32 + j) * 66 + node_l] * qp[j];
    red[tid] = acc;
    __syncthreads();
    if (tid < 64) {
        float e = red[tid] + red[tid + 64] + red[tid + 128] + red[tid + 192];
        el[tid] = e;
        if (n0 + tid < N) e_out[n0 + tid] = e;
    }
    __syncthreads();
    if (tid < 64) {
        int gg = gl[tid];
        if (gg >= 0 && (tid == 0 || gl[tid - 1] != gg)) {
            float m = el[tid];
            for (int j = tid + 1; j < 64 && gl[j] == gg; ++j) m = fmaxf(m, el[j]);
            atomicMax(&emax[gg], fenc(m));
        }
    }
}

// ---------------- fused softmax-denominator + weighted pooling (per graph) ----------------
__launch_bounds__(256)
__global__ void k_r2(const float* __restrict__ h, const float* __restrict__ x,
                     const float* __restrict__ e_buf, const unsigned* __restrict__ emax,
                     const int* __restrict__ gs, const int* __restrict__ ge,
                     float* __restrict__ q_star) {
    __shared__ float exs[256];
    __shared__ float red[256];
    int g = blockIdx.x, tid = threadIdx.x;
    int s0 = gs[g], s1 = ge[g];
    if (s1 <= s0) {
        if (tid < 128) q_star[g * 256 + 128 + tid] = 0.0f;
        return;
    }
    float m = fdec(emax[g]);
    int d = tid & 127, c = tid >> 7;
    float acc = 0.0f, den_acc = 0.0f;
    for (int base = s0; base < s1; base += 256) {
        int n = base + tid;
        float ex = (n < s1) ? expf(e_buf[n] - m) : 0.0f;
        __syncthreads();
        exs[tid] = ex;
        den_acc += ex;
        __syncthreads();
        int lim = min(256, s1 - base);
        for (int j = c; j < lim; j += 2) {
            int n2 = base + j;
            float na = (d < 64) ? h[(size_t)n2 * 64 + d] : x[(size_t)n2 * 64 + (d - 64)];
            acc += na * exs[j];
        }
    }
    red[tid] = den_acc;
    __syncthreads();
    for (int s = 128; s > 0; s >>= 1) {
        if (tid < s) red[tid] += red[tid + s];
        __syncthreads();
    }
    float den = red[0];
    __syncthreads();
    red[tid] = acc;
    __syncthreads();
    if (tid < 128)
        q_star[g * 256 + 128 + tid] = (red[tid] + red[tid + 128]) / den;
}

// ---------------- head GEMM layer: C = act(A @ W + b), tiled MFMA ----------------
// grid (16, NT16/4); block 256. MODE: 0=PReLU, 1=ReLU, 2=tanh.
template<int MODE>
__launch_bounds__(256)
__global__ void k_hgemm(const float* __restrict__ A, const short* __restrict__ Bf,
                        const float* __restrict__ bias, const float* __restrict__ pa,
                        float* __restrict__ Cout, int K, int NT16) {
    int tid = threadIdx.x, lane = tid & 63, nt = tid >> 6;
    int quad = lane >> 4, col = lane & 15;
    int s0 = blockIdx.x * 16;
    int ntile = blockIdx.y * 4 + nt;
    int NoutTot = NT16 * 16;
    const short8* F = (const short8*)Bf;
    floatx4 T = {0.0f, 0.0f, 0.0f, 0.0f};
    const float* ap = A + (size_t)(s0 + col) * K + quad * 8;
    int KT = K >> 5;
#pragma unroll 4
    for (int kt = 0; kt < KT; ++kt) {
        short8 ah, al;
        cvt8(ap + kt * 32, ah, al);
        int t = kt * NT16 + ntile;
        short8 bh = F[(t * 2 + 0) * 64 + lane];
        short8 bl = F[(t * 2 + 1) * 64 + lane];
        T = __builtin_amdgcn_mfma_f32_16x16x32_bf16(ah, bh, T, 0, 0, 0);
        T = __builtin_amdgcn_mfma_f32_16x16x32_bf16(al, bh, T, 0, 0, 0);
        T = __builtin_amdgcn_mfma_f32_16x16x32_bf16(ah, bl, T, 0, 0, 0);
    }
    int o = ntile * 16 + col;
    float b = bias[o];
    float a = (MODE == 0) ? pa[0] : 0.0f;
#pragma unroll
    for (int r = 0; r < 4; ++r) {
        float v = T[r] + b;
        if (MODE == 0) v = (v >= 0.0f) ? v : a * v;
        if (MODE == 1) v = fmaxf(v, 0.0f);
        if (MODE == 2) v = tanhf(v);
        Cout[(size_t)(s0 + quad * 4 + r) * NoutTot + o] = v;
    }
}

// ---------------- head output layer + softmax: out = softmax(A @ oW + ob) ----------------
// grid 16; block 256; K=512, Nout padded to 64 (cols >= 54 unused).
__launch_bounds__(256)
__global__ void k_hout(const float* __restrict__ A, const short* __restrict__ Bf,
                       const float* __restrict__ ob, float* __restrict__ out) {
    __shared__ float sm[16][64];
    __shared__ float smax[16], sinv[16];
    int tid = threadIdx.x, lane = tid & 63, nt = tid >> 6;
    int quad = lane >> 4, col = lane & 15;
    int s0 = blockIdx.x * 16;
    const short8* F = (const short8*)Bf;
    floatx4 T = {0.0f, 0.0f, 0.0f, 0.0f};
    const float* ap = A + (size_t)(s0 + col) * 512 + quad * 8;
#pragma unroll 4
    for (int kt = 0; kt < 16; ++kt) {
        short8 ah, al;
        cvt8(ap + kt * 32, ah, al);
        int t = kt * 4 + nt;
        short8 bh = F[(t * 2 + 0) * 64 + lane];
        short8 bl = F[(t * 2 + 1) * 64 + lane];
        T = __builtin_amdgcn_mfma_f32_16x16x32_bf16(ah, bh, T, 0, 0, 0);
        T = __builtin_amdgcn_mfma_f32_16x16x32_bf16(al, bh, T, 0, 0, 0);
        T = __builtin_amdgcn_mfma_f32_16x16x32_bf16(ah, bl, T, 0, 0, 0);
    }
    int o = nt * 16 + col;
    float b = (o < 54) ? ob[o] : 0.0f;
#pragma unroll
    for (int r = 0; r < 4; ++r)
        sm[quad * 4 + r][o] = (o < 54) ? (T[r] + b) : -1e30f;
    __syncthreads();
    if (tid < 16) {
        float m = -INFINITY;
        for (int j = 0; j < 54; ++j) m = fmaxf(m, sm[tid][j]);
        float s = 0.0f;
        for (int j = 0; j < 54; ++j) s += expf(sm[tid][j] - m);
        smax[tid] = m;
        sinv[tid] = 1.0f / s;
    }
    __syncthreads();
    for (int idx = tid; idx < 16 * 54; idx += 256) {
        int srow = idx / 54, oo = idx % 54;
        out[(size_t)(s0 + srow) * 54 + oo] = expf(sm[srow][oo] - smax[srow]) * sinv[srow];
    }
}

// ---------------- driver ----------------
extern "C" void kernel_launch(void* const* d_in, const int* in_sizes, int n_in,
                              void* d_out, int out_size, void* d_ws, size_t ws_size,
                              hipStream_t stream) {
    const float* node_attr = (const float*)d_in[0];
    const float* edge_attr = (const float*)d_in[1];
    const float* edge_len  = (const float*)d_in[2];
    const int*   src       = (const int*)d_in[3];
    const int*   dst       = (const int*)d_in[4];
    const int*   node_grph = (const int*)d_in[5];
    const float* proj_W    = (const float*)d_in[6];
    const float* proj_b    = (const float*)d_in[7];
    const float* centers   = (const float*)d_in[8];
    const float* beta      = (const float*)d_in[9];
    const float* bond_W    = (const float*)d_in[10];
    const float* bond_b    = (const float*)d_in[11];
    const float* conv_b    = (const float*)d_in[12];
    const float* gru_Wih   = (const float*)d_in[13];
    const float* gru_Whh   = (const float*)d_in[14];
    const float* gru_bih   = (const float*)d_in[15];
    const float* gru_bhh   = (const float*)d_in[16];
    const float* lWih0     = (const float*)d_in[17];
    const float* lWhh0     = (const float*)d_in[18];
    const float* lbih0     = (const float*)d_in[19];
    const float* lbhh0     = (const float*)d_in[20];
    const float* lWih1     = (const float*)d_in[21];
    const float* lWhh1     = (const float*)d_in[22];
    const float* lbih1     = (const float*)d_in[23];
    const float* lbhh1     = (const float*)d_in[24];
    const float* sp_W      = (const float*)d_in[25];
    const float* sp_b      = (const float*)d_in[26];
    const float* prelu_a   = (const float*)d_in[27];
    const float* h0_W1     = (const float*)d_in[28];
    const float* h0_b1     = (const float*)d_in[29];
    const float* h0_W2     = (const float*)d_in[30];
    const float* h0_b2     = (const float*)d_in[31];
    const float* out_W     = (const float*)d_in[32];
    const float* out_b     = (const float*)d_in[33];
    float* out = (float*)d_out;

    float* ws = (float*)d_ws;
    size_t off = 0;
    float* x      = ws + off; off += (size_t)N * 64;
    float* h      = ws + off; off += (size_t)N * 64;
    float* ef_t   = ws + off; off += (size_t)E * 17;   // 1.7M floats; reused by head after MP loop
    float* agg    = ws + off; off += (size_t)N * 64;
    float* wfrag  = ws + off; off += 17 * 16 * 64 * 8 / 2;
    float* fgI    = ws + off; off += 2 * 64 * 192 / 2;  // gru Wih frags (24576 shorts)
    float* fgH    = ws + off; off += 2 * 64 * 192 / 2;
    float* lW0T   = ws + off; off += 256 * 512;
    float* lU0T   = ws + off; off += 128 * 512;
    float* lW1T   = ws + off; off += 128 * 512;
    float* lU1T   = ws + off; off += 128 * 512;
    float* h0     = ws + off; off += B * 128;
    float* c0     = ws + off; off += B * 128;
    float* h1     = ws + off; off += B * 128;
    float* c1     = ws + off; off += B * 128;
    float* q_star = ws + off; off += B * 256;
    float* e_buf  = ws + off; off += N;
    unsigned* emax = (unsigned*)(ws + off); off += B;
    int* gs       = (int*)(ws + off); off += B;
    int* ge       = (int*)(ws + off); off += B;

    // head buffers alias the ef_t region (dead after the MP loop):
    //   fsp 131072f | fw1 262144f | fw2 262144f | fow 32768f | hb1 131072f | hb2 131072f  (= 950272 < 1.7M)
    short* fsp = (short*)ef_t;
    short* fw1 = (short*)(ef_t + 131072);
    short* fw2 = (short*)(ef_t + 131072 + 262144);
    short* fow = (short*)(ef_t + 131072 + 2 * 262144);
    float* hb1 = ef_t + 131072 + 2 * 262144 + 32768;
    float* hb2 = hb1 + 131072;

    // LSTM weight transposes (PyTorch (out,in) -> (in,out))
    k_transpose<<<(512 * 256 + 255) / 256, 256, 0, stream>>>(lWih0, lW0T, 512, 256);
    k_transpose<<<(512 * 128 + 255) / 256, 256, 0, stream>>>(lWhh0, lU0T, 512, 128);
    k_transpose<<<(512 * 128 + 255) / 256, 256, 0, stream>>>(lWih1, lW1T, 512, 128);
    k_transpose<<<(512 * 128 + 255) / 256, 256, 0, stream>>>(lWhh1, lU1T, 512, 128);

    // bond weights -> split-bf16 MFMA fragment layout
    k_prepW<<<(17 * 4 * 2 * 64 + 255) / 256, 256, 0, stream>>>(bond_W, bond_b, (short*)wfrag);
    // GRU weights -> fragments (PyTorch (192,64) layout, trans=1)
    k_prepB<<<6, 256, 0, stream>>>(gru_Wih, (short*)fgI, 12, 64, 1, 192, 2 * 12 * 64);
    k_prepB<<<6, 256, 0, stream>>>(gru_Whh, (short*)fgH, 12, 64, 1, 192, 2 * 12 * 64);

    // zero LSTM state + q_star (contiguous region: h0,c0,h1,c1,q_star)
    k_fill<<<(4 * B * 128 + B * 256 + 255) / 256, 256, 0, stream>>>(h0, 0.0f, 4 * B * 128 + B * 256);

    k_proj<<<N / 16, 256, 0, stream>>>(node_attr, proj_W, proj_b, x, h);
    k_efeat<<<(E + 255) / 256, 256, 0, stream>>>(edge_attr, edge_len, centers, beta, ef_t);

    k_binit<<<1, 256, 0, stream>>>(gs, ge);
    k_bounds<<<(N + 255) / 256, 256, 0, stream>>>(node_grph, gs, ge);

    for (int step = 0; step < 4; ++step) {
        k_agginit<<<(N * 64 + 255) / 256, 256, 0, stream>>>(agg, conv_b);
        k_msg2<<<(E + 63) / 64, 256, 0, stream>>>(h, ef_t, (const short*)wfrag, src, dst, agg);
        k_gru2<<<(N + 31) / 32, 256, 0, stream>>>(agg, h, (const short*)fgI, (const short*)fgH,
                                                  gru_bih, gru_bhh);
    }

    // head fragment prep (ef_t region now dead; weights are (in,out) so trans=0)
    k_prepB<<<64, 256, 0, stream>>>(sp_W, fsp, 32, 512, 0, 512, 8 * 32 * 64);
    k_prepB<<<128, 256, 0, stream>>>(h0_W1, fw1, 32, 512, 0, 512, 16 * 32 * 64);
    k_prepB<<<128, 256, 0, stream>>>(h0_W2, fw2, 32, 512, 0, 512, 16 * 32 * 64);
    k_prepB<<<16, 256, 0, stream>>>(out_W, fow, 4, 54, 0, 54, 16 * 4 * 64);

    for (int it = 0; it < 3; ++it) {
        k_lstm<<<B, 256, 0, stream>>>(h0, c0, h1, c1, q_star,
                                      lW0T, lU0T, lbih0, lbhh0,
                                      lW1T, lU1T, lbih1, lbhh1, emax);
        k_e2<<<(N + 63) / 64, 256, 0, stream>>>(h, x, h1, node_grph, e_buf, emax);
        k_r2<<<B, 256, 0, stream>>>(h, x, e_buf, emax, gs, ge, q_star);
    }

    // head: 3 MFMA GEMM layers + fused output/softmax
    k_hgemm<0><<<dim3(16, 8), 256, 0, stream>>>(q_star, fsp, sp_b, prelu_a, hb1, 256, 32);
    k_hgemm<1><<<dim3(16, 8), 256, 0, stream>>>(hb1, fw1, h0_b1, nullptr, hb2, 512, 32);
    k_hgemm<2><<<dim3(16, 8), 256, 0, stream>>>(hb2, fw2, h0_b2, nullptr, hb1, 512, 32);
    k_hout<<<16, 256, 0, stream>>>(hb1, fow, out_b, out);
}

// Round 5
// 917.551 us; speedup vs baseline: 2.6356x; 1.0481x over previous
//
#include <hip/hip_runtime.h>
#include <math.h>

constexpr int N = 50000;     // nodes
constexpr int E = 100000;    // edges
constexpr int B = 256;       // graphs
constexpr int H = 64;
constexpr int DN = 110;

#define DEV __device__ __forceinline__

typedef __attribute__((ext_vector_type(8))) short short8;
typedef __attribute__((ext_vector_type(4))) float floatx4;

DEV float sigf(float x) { return 1.0f / (1.0f + expf(-x)); }

DEV unsigned fenc(float x) {
    unsigned u = __float_as_uint(x);
    return (u & 0x80000000u) ? ~u : (u | 0x80000000u);
}
DEV float fdec(unsigned u) {
    return (u & 0x80000000u) ? __uint_as_float(u & 0x7fffffffu) : __uint_as_float(~u);
}

// bf16 round-to-nearest-even conversion (manual, header-type-free)
DEV short f2bf(float f) {
    unsigned u = __float_as_uint(f);
    unsigned r = (u + 0x7fffu + ((u >> 16) & 1u)) >> 16;
    return (short)r;
}
DEV float bf2f(short s) { return __uint_as_float(((unsigned)(unsigned short)s) << 16); }

// convert 8 contiguous floats -> hi/lo bf16 fragments
DEV void cvt8(const float* p, short8& hi, short8& lo) {
    float4 u0 = *(const float4*)p;
    float4 u1 = *(const float4*)(p + 4);
    float vv[8] = {u0.x, u0.y, u0.z, u0.w, u1.x, u1.y, u1.z, u1.w};
#pragma unroll
    for (int j = 0; j < 8; ++j) {
        short hb = f2bf(vv[j]);
        hi[j] = hb;
        lo[j] = f2bf(vv[j] - bf2f(hb));
    }
}

// ---------------- generic helpers ----------------
__global__ void k_fill(float* p, float v, int n) {
    int i = blockIdx.x * 256 + threadIdx.x;
    if (i < n) p[i] = v;
}

// out[c*R + r] = in[r*C + c]   (in is R x C)
__global__ void k_transpose(const float* in, float* out, int R, int C) {
    int idx = blockIdx.x * 256 + threadIdx.x;
    if (idx < R * C) {
        int r = idx / C, c = idx % C;
        out[c * R + r] = in[idx];
    }
}

// ---------------- generic B-fragment prep (split bf16 hi/lo) ----------------
__global__ void k_prepB(const float* __restrict__ W, short* __restrict__ out,
                        int NT16, int ld, int trans, int ocap, int total) {
    int idx = blockIdx.x * 256 + threadIdx.x;
    if (idx >= total) return;
    int lane = idx & 63;
    int t = idx >> 6;
    int ntile = t % NT16;
    int kt = t / NT16;
    int quad = lane >> 4, col = lane & 15;
    int o = ntile * 16 + col;
    short hi[8], lo[8];
#pragma unroll
    for (int j = 0; j < 8; ++j) {
        int k = kt * 32 + quad * 8 + j;
        float v = 0.0f;
        if (o < ocap) v = trans ? W[(size_t)o * ld + k] : W[(size_t)k * ld + o];
        short hb = f2bf(v);
        hi[j] = hb;
        lo[j] = f2bf(v - bf2f(hb));
    }
    short* dh = out + (((size_t)(t * 2 + 0) * 64 + lane) * 8);
    short* dl = out + (((size_t)(t * 2 + 1) * 64 + lane) * 8);
#pragma unroll
    for (int j = 0; j < 8; ++j) { dh[j] = hi[j]; dl[j] = lo[j]; }
}

// ---------------- projection: x = relu(na @ W + b); h = x ----------------
__launch_bounds__(256)
__global__ void k_proj(const float* __restrict__ na, const float* __restrict__ W,
                       const float* __restrict__ b, float* __restrict__ x, float* __restrict__ h) {
    __shared__ float Ws[DN * 64];
    __shared__ float as[16][112];
    int tid = threadIdx.x;
    for (int i = tid; i < DN * 64; i += 256) Ws[i] = W[i];
    int n0 = blockIdx.x * 16;
    for (int i = tid; i < 16 * DN; i += 256) {
        int nn = i / DN, ii = i % DN;
        as[nn][ii] = na[(n0 + nn) * DN + ii];
    }
    __syncthreads();
    int o = tid & 63, ng = tid >> 6;
    float bo = b[o];
    for (int j = 0; j < 4; ++j) {
        int nn = ng * 4 + j;
        float acc = bo;
#pragma unroll 10
        for (int i = 0; i < DN; ++i) acc += as[nn][i] * Ws[i * 64 + o];
        float v = fmaxf(acc, 0.0f);
        int n = n0 + nn;
        x[n * 64 + o] = v;
        h[n * 64 + o] = v;
    }
}

// ---------------- edge features -> transposed layout ef_t[kk][e], kk 0..16 ----------------
__global__ void k_efeat(const float* __restrict__ ea, const float* __restrict__ el,
                        const float* __restrict__ centers, const float* __restrict__ beta,
                        float* __restrict__ ef_t) {
    int e = blockIdx.x * 256 + threadIdx.x;
    if (e >= E) return;
    float L = el[e];
#pragma unroll
    for (int j = 0; j < 8; ++j) ef_t[j * E + e] = ea[e * 8 + j];
#pragma unroll
    for (int j = 0; j < 8; ++j) {
        float d = L - centers[j];
        ef_t[(8 + j) * E + e] = expf(-beta[j] * d * d);
    }
    ef_t[16 * E + e] = 1.0f;
}

// ---------------- agg init with conv bias ----------------
__global__ void k_agginit(float* __restrict__ agg, const float* __restrict__ conv_b) {
    int idx = blockIdx.x * 256 + threadIdx.x;
    if (idx < N * 64) agg[idx] = conv_b[idx & 63];
}

// ---------------- precompute bond_W (+bond_b as kk=16) into MFMA B-fragment layout ----------------
__global__ void k_prepW(const float* __restrict__ bond_W, const float* __restrict__ bond_b,
                        short* __restrict__ wf) {
    int idx = blockIdx.x * 256 + threadIdx.x;
    if (idx >= 17 * 4 * 2 * 64) return;
    int lane = idx & 63;
    int t = idx >> 6;            // (kk*4+nt)*2+ks
    int ks = t & 1;
    int nt = (t >> 1) & 3;
    int kk = t >> 3;
    const float* S = (kk < 16) ? (bond_W + kk * 4096) : bond_b;
    int quad = lane >> 4, col = lane & 15;
    short hi[8], lo[8];
#pragma unroll
    for (int j = 0; j < 8; ++j) {
        int i = ks * 32 + quad * 8 + j;
        float v = S[i * 64 + nt * 16 + col];
        short hb = f2bf(v);
        hi[j] = hb;
        lo[j] = f2bf(v - bf2f(hb));
    }
    short* dh = wf + (((size_t)(t * 2 + 0) * 64 + lane) * 8);
    short* dl = wf + (((size_t)(t * 2 + 1) * 64 + lane) * 8);
#pragma unroll
    for (int j = 0; j < 8; ++j) { dh[j] = hi[j]; dl[j] = lo[j]; }
}

// ---------------- message GEMM via split-bf16 MFMA + scatter-add (128 edges/block) ----------------
// Block = 128 edges x 64 outputs; each wave handles o-slice nt*16..+15 for all 8 m-tiles.
// Weight frags (278 KB) read once per block -> M=128 halves the dominant L2 traffic vs M=64.
__launch_bounds__(256, 1)
__global__ void k_msg3(const float* __restrict__ feat, const float* __restrict__ ef_t,
                       const short* __restrict__ wf,
                       const int* __restrict__ src, const int* __restrict__ dst,
                       float* __restrict__ agg) {
    __shared__ float efs[17 * 128];   // [kk][e_local]
    __shared__ int srcs[128];
    __shared__ int dsts[128];

    int tid = threadIdx.x;
    int e0 = blockIdx.x * 128;
    int lane = tid & 63;
    int nt = tid >> 6;
    int quad = lane >> 4, col = lane & 15;

    if (tid < 128) {
        int eg = e0 + tid;
        srcs[tid] = (eg < E) ? src[eg] : 0;
        dsts[tid] = (eg < E) ? dst[eg] : 0;
    }
    for (int i = tid; i < 17 * 128; i += 256) {
        int kk = i >> 7, e = i & 127;
        int eg = e0 + e;
        efs[i] = (eg < E) ? ef_t[kk * E + eg] : 0.0f;   // pad edges: ef=0 -> C=0
    }
    __syncthreads();

    // A fragments (feat, split hi/lo), constant across kk; 8 m-tiles
    short8 Ah[8][2], Al[8][2];
#pragma unroll
    for (int mt = 0; mt < 8; ++mt) {
        int s = srcs[mt * 16 + col];
        const float* fp = feat + (size_t)s * 64 + quad * 8;
#pragma unroll
        for (int ks = 0; ks < 2; ++ks) cvt8(fp + ks * 32, Ah[mt][ks], Al[mt][ks]);
    }

    const short8* Wf = (const short8*)wf;
    float C[8][4] = {};

#pragma unroll 1
    for (int kk = 0; kk < 17; ++kk) {
        int tb = (kk * 4 + nt) * 2;
        short8 Bh0 = Wf[((tb + 0) * 2 + 0) * 64 + lane];
        short8 Bh1 = Wf[((tb + 1) * 2 + 0) * 64 + lane];
        short8 Bl0 = Wf[((tb + 0) * 2 + 1) * 64 + lane];
        short8 Bl1 = Wf[((tb + 1) * 2 + 1) * 64 + lane];

#pragma unroll
        for (int mt = 0; mt < 8; ++mt) {
            floatx4 T = {0.0f, 0.0f, 0.0f, 0.0f};
            T = __builtin_amdgcn_mfma_f32_16x16x32_bf16(Ah[mt][0], Bh0, T, 0, 0, 0);
            T = __builtin_amdgcn_mfma_f32_16x16x32_bf16(Ah[mt][1], Bh1, T, 0, 0, 0);
            T = __builtin_amdgcn_mfma_f32_16x16x32_bf16(Al[mt][0], Bh0, T, 0, 0, 0);
            T = __builtin_amdgcn_mfma_f32_16x16x32_bf16(Al[mt][1], Bh1, T, 0, 0, 0);
            T = __builtin_amdgcn_mfma_f32_16x16x32_bf16(Ah[mt][0], Bl0, T, 0, 0, 0);
            T = __builtin_amdgcn_mfma_f32_16x16x32_bf16(Ah[mt][1], Bl1, T, 0, 0, 0);
            float4 ef = *(const float4*)&efs[kk * 128 + mt * 16 + quad * 4];
            C[mt][0] += ef.x * T[0];
            C[mt][1] += ef.y * T[1];
            C[mt][2] += ef.z * T[2];
            C[mt][3] += ef.w * T[3];
        }
    }

    int o = nt * 16 + col;
#pragma unroll
    for (int mt = 0; mt < 8; ++mt) {
#pragma unroll
        for (int r = 0; r < 4; ++r) {
            int e_l = mt * 16 + quad * 4 + r;
            if (e0 + e_l < E) {
                atomicAdd(agg + (size_t)dsts[e_l] * 64 + o, C[mt][r]);
            }
        }
    }
}

// ---------------- GRU step via split-bf16 MFMA: h = GRU(relu(agg), h) ----------------
__launch_bounds__(256)
__global__ void k_gru2(const float* __restrict__ agg, float* __restrict__ h,
                       const short* __restrict__ fI, const short* __restrict__ fH,
                       const float* __restrict__ bih, const float* __restrict__ bhh) {
    int tid = threadIdx.x, lane = tid & 63, nt = tid >> 6;
    int quad = lane >> 4, col = lane & 15;
    int n0 = blockIdx.x * 32;

    short8 Gh[2][2], Gl[2][2], Hh[2][2], Hl[2][2];
#pragma unroll
    for (int mt = 0; mt < 2; ++mt) {
        int node = n0 + mt * 16 + col;
        bool ok = node < N;
        size_t base = (size_t)(ok ? node : 0) * 64 + quad * 8;
#pragma unroll
        for (int ks = 0; ks < 2; ++ks) {
            float4 a0 = *(const float4*)(agg + base + ks * 32);
            float4 a1 = *(const float4*)(agg + base + ks * 32 + 4);
            float4 h0 = *(const float4*)(h + base + ks * 32);
            float4 h1 = *(const float4*)(h + base + ks * 32 + 4);
            float gv[8] = {a0.x, a0.y, a0.z, a0.w, a1.x, a1.y, a1.z, a1.w};
            float hv[8] = {h0.x, h0.y, h0.z, h0.w, h1.x, h1.y, h1.z, h1.w};
#pragma unroll
            for (int j = 0; j < 8; ++j) {
                float g = ok ? fmaxf(gv[j], 0.0f) : 0.0f;
                float hh = ok ? hv[j] : 0.0f;
                short gb = f2bf(g);
                Gh[mt][ks][j] = gb;
                Gl[mt][ks][j] = f2bf(g - bf2f(gb));
                short hb = f2bf(hh);
                Hh[mt][ks][j] = hb;
                Hl[mt][ks][j] = f2bf(hh - bf2f(hb));
            }
        }
    }
    __syncthreads();  // all h reads complete before any wave writes h below

    const short8* FI = (const short8*)fI;
    const short8* FH = (const short8*)fH;
    floatx4 aI[2][3] = {}, aH[2][3] = {};
#pragma unroll
    for (int ks = 0; ks < 2; ++ks) {
        short8 bIh[3], bIl[3], bHh[3], bHl[3];
#pragma unroll
        for (int g = 0; g < 3; ++g) {
            int t = ks * 12 + g * 4 + nt;   // NT16 = 12 (Nout=192)
            bIh[g] = FI[(t * 2 + 0) * 64 + lane];
            bIl[g] = FI[(t * 2 + 1) * 64 + lane];
            bHh[g] = FH[(t * 2 + 0) * 64 + lane];
            bHl[g] = FH[(t * 2 + 1) * 64 + lane];
        }
#pragma unroll
        for (int mt = 0; mt < 2; ++mt) {
#pragma unroll
            for (int g = 0; g < 3; ++g) {
                aI[mt][g] = __builtin_amdgcn_mfma_f32_16x16x32_bf16(Gh[mt][ks], bIh[g], aI[mt][g], 0, 0, 0);
                aI[mt][g] = __builtin_amdgcn_mfma_f32_16x16x32_bf16(Gl[mt][ks], bIh[g], aI[mt][g], 0, 0, 0);
                aI[mt][g] = __builtin_amdgcn_mfma_f32_16x16x32_bf16(Gh[mt][ks], bIl[g], aI[mt][g], 0, 0, 0);
                aH[mt][g] = __builtin_amdgcn_mfma_f32_16x16x32_bf16(Hh[mt][ks], bHh[g], aH[mt][g], 0, 0, 0);
                aH[mt][g] = __builtin_amdgcn_mfma_f32_16x16x32_bf16(Hl[mt][ks], bHh[g], aH[mt][g], 0, 0, 0);
                aH[mt][g] = __builtin_amdgcn_mfma_f32_16x16x32_bf16(Hh[mt][ks], bHl[g], aH[mt][g], 0, 0, 0);
            }
        }
    }

    int o = nt * 16 + col;
    float br = bih[o], bz = bih[64 + o], bn = bih[128 + o];
    float cr = bhh[o], cz = bhh[64 + o], cn = bhh[128 + o];
#pragma unroll
    for (int mt = 0; mt < 2; ++mt) {
#pragma unroll
        for (int r = 0; r < 4; ++r) {
            int node = n0 + mt * 16 + quad * 4 + r;
            if (node >= N) continue;
            float rg = sigf(aI[mt][0][r] + br + aH[mt][0][r] + cr);
            float z  = sigf(aI[mt][1][r] + bz + aH[mt][1][r] + cz);
            float ng = tanhf(aI[mt][2][r] + bn + rg * (aH[mt][2][r] + cn));
            float hold = h[(size_t)node * 64 + o];
            h[(size_t)node * 64 + o] = (1.0f - z) * ng + z * hold;
        }
    }
}

// ---------------- graph bounds: sorted node_graph -> boundary detection, no atomics ----------------
__global__ void k_bounds2(const int* __restrict__ ng, int* __restrict__ gs, int* __restrict__ ge) {
    int n = blockIdx.x * 256 + threadIdx.x;
    if (n >= N) return;
    int g = ng[n];
    int gp = (n == 0) ? -1 : ng[n - 1];
    if (g != gp) {
        gs[g] = n;
        if (n > 0) ge[gp] = n;
        for (int q = gp + 1; q < g; ++q) { gs[q] = 0; ge[q] = 0; }  // empty graphs
    }
    if (n == N - 1) {
        ge[g] = N;
        for (int q = g + 1; q < B; ++q) { gs[q] = 0; ge[q] = 0; }
    }
}

// ---------------- Set2Set: 2-layer LSTM, one block per sample ----------------
__launch_bounds__(256)
__global__ void k_lstm(float* __restrict__ h0, float* __restrict__ c0,
                       float* __restrict__ h1, float* __restrict__ c1,
                       float* __restrict__ q_star,
                       const float* __restrict__ W0T, const float* __restrict__ U0T,
                       const float* __restrict__ b0i, const float* __restrict__ b0h,
                       const float* __restrict__ W1T, const float* __restrict__ U1T,
                       const float* __restrict__ b1i, const float* __restrict__ b1h,
                       unsigned* __restrict__ emax) {
    __shared__ float xb[256], hb[128], gb[512], h0n[128];
    int s = blockIdx.x, tid = threadIdx.x;
    if (tid == 0) emax[s] = fenc(-INFINITY);
    xb[tid] = q_star[s * 256 + tid];
    if (tid < 128) hb[tid] = h0[s * 128 + tid];
    __syncthreads();
    float g0 = b0i[tid] + b0h[tid];
    float g1 = b0i[tid + 256] + b0h[tid + 256];
    for (int i = 0; i < 256; ++i) {
        float x = xb[i];
        g0 += x * W0T[i * 512 + tid];
        g1 += x * W0T[i * 512 + tid + 256];
    }
    for (int i = 0; i < 128; ++i) {
        float hh = hb[i];
        g0 += hh * U0T[i * 512 + tid];
        g1 += hh * U0T[i * 512 + tid + 256];
    }
    gb[tid] = g0; gb[tid + 256] = g1;
    __syncthreads();
    if (tid < 128) {
        float ii = gb[tid], ff = gb[128 + tid], gg = gb[256 + tid], oo = gb[384 + tid];
        float c = sigf(ff) * c0[s * 128 + tid] + sigf(ii) * tanhf(gg);
        float hn = sigf(oo) * tanhf(c);
        c0[s * 128 + tid] = c; h0[s * 128 + tid] = hn; h0n[tid] = hn;
        hb[tid] = h1[s * 128 + tid];
    }
    __syncthreads();
    float ga = b1i[tid] + b1h[tid];
    float gbv = b1i[tid + 256] + b1h[tid + 256];
    for (int i = 0; i < 128; ++i) {
        float x = h0n[i], hh = hb[i];
        ga  += x * W1T[i * 512 + tid]       + hh * U1T[i * 512 + tid];
        gbv += x * W1T[i * 512 + tid + 256] + hh * U1T[i * 512 + tid + 256];
    }
    gb[tid] = ga; gb[tid + 256] = gbv;
    __syncthreads();
    if (tid < 128) {
        float ii = gb[tid], ff = gb[128 + tid], gg = gb[256 + tid], oo = gb[384 + tid];
        float c = sigf(ff) * c1[s * 128 + tid] + sigf(ii) * tanhf(gg);
        float hn = sigf(oo) * tanhf(c);
        c1[s * 128 + tid] = c; h1[s * 128 + tid] = hn;
        q_star[s * 256 + tid] = hn;
        q_star[s * 256 + 128 + tid] = 0.f;
    }
}

// ---------------- attention: e[n] = dot([h|x][n], q[g]); block = 64 nodes, LDS tile ----------------
__launch_bounds__(256)
__global__ void k_e2(const float* __restrict__ h, const float* __restrict__ x,
                     const float* __restrict__ q, const int* __restrict__ ngr,
                     float* __restrict__ e_out, unsigned* __restrict__ emax) {
    __shared__ float nas[128 * 66];
    __shared__ float red[256];
    __shared__ int gl[64];
    __shared__ float el[64];
    int tid = threadIdx.x;
    int n0 = blockIdx.x * 64;
    for (int i = tid; i < 64 * 64; i += 256) {
        int node = i >> 6, d = i & 63;
        int n = n0 + node;
        float hv = (n < N) ? h[(size_t)n * 64 + d] : 0.0f;
        float xv = (n < N) ? x[(size_t)n * 64 + d] : 0.0f;
        nas[d * 66 + node] = hv;
        nas[(64 + d) * 66 + node] = xv;
    }
    if (tid < 64) {
        int n = n0 + tid;
        gl[tid] = (n < N) ? ngr[n] : -1;
    }
    __syncthreads();
    int node_l = tid & 63, part = tid >> 6;
    int g = gl[node_l];
    const float* qp = q + (size_t)((g < 0) ? 0 : g) * 128 + part * 32;
    float acc = 0.0f;
#pragma unroll 8
    for (int j = 0; j < 32; ++j)
        acc += nas[(part * 32 + j) * 66 + node_l] * qp[j];
    red[tid] = acc;
    __syncthreads();
    if (tid < 64) {
        float e = red[tid] + red[tid + 64] + red[tid + 128] + red[tid + 192];
        el[tid] = e;
        if (n0 + tid < N) e_out[n0 + tid] = e;
    }
    __syncthreads();
    if (tid < 64) {
        int gg = gl[tid];
        if (gg >= 0 && (tid == 0 || gl[tid - 1] != gg)) {
            float m = el[tid];
            for (int j = tid + 1; j < 64 && gl[j] == gg; ++j) m = fmaxf(m, el[j]);
            atomicMax(&emax[gg], fenc(m));
        }
    }
}

// ---------------- fused softmax-denominator + weighted pooling (per graph) ----------------
__launch_bounds__(256)
__global__ void k_r2(const float* __restrict__ h, const float* __restrict__ x,
                     const float* __restrict__ e_buf, const unsigned* __restrict__ emax,
                     const int* __restrict__ gs, const int* __restrict__ ge,
                     float* __restrict__ q_star) {
    __shared__ float exs[256];
    __shared__ float red[256];
    int g = blockIdx.x, tid = threadIdx.x;
    int s0 = gs[g], s1 = ge[g];
    if (s1 <= s0) {
        if (tid < 128) q_star[g * 256 + 128 + tid] = 0.0f;
        return;
    }
    float m = fdec(emax[g]);
    int d = tid & 127, c = tid >> 7;
    float acc = 0.0f, den_acc = 0.0f;
    for (int base = s0; base < s1; base += 256) {
        int n = base + tid;
        float ex = (n < s1) ? expf(e_buf[n] - m) : 0.0f;
        __syncthreads();
        exs[tid] = ex;
        den_acc += ex;
        __syncthreads();
        int lim = min(256, s1 - base);
        for (int j = c; j < lim; j += 2) {
            int n2 = base + j;
            float na = (d < 64) ? h[(size_t)n2 * 64 + d] : x[(size_t)n2 * 64 + (d - 64)];
            acc += na * exs[j];
        }
    }
    red[tid] = den_acc;
    __syncthreads();
    for (int s = 128; s > 0; s >>= 1) {
        if (tid < s) red[tid] += red[tid + s];
        __syncthreads();
    }
    float den = red[0];
    __syncthreads();
    red[tid] = acc;
    __syncthreads();
    if (tid < 128)
        q_star[g * 256 + 128 + tid] = (red[tid] + red[tid + 128]) / den;
}

// ---------------- head GEMM layer: C = act(A @ W + b), tiled MFMA ----------------
template<int MODE>
__launch_bounds__(256)
__global__ void k_hgemm(const float* __restrict__ A, const short* __restrict__ Bf,
                        const float* __restrict__ bias, const float* __restrict__ pa,
                        float* __restrict__ Cout, int K, int NT16) {
    int tid = threadIdx.x, lane = tid & 63, nt = tid >> 6;
    int quad = lane >> 4, col = lane & 15;
    int s0 = blockIdx.x * 16;
    int ntile = blockIdx.y * 4 + nt;
    int NoutTot = NT16 * 16;
    const short8* F = (const short8*)Bf;
    floatx4 T = {0.0f, 0.0f, 0.0f, 0.0f};
    const float* ap = A + (size_t)(s0 + col) * K + quad * 8;
    int KT = K >> 5;
#pragma unroll 4
    for (int kt = 0; kt < KT; ++kt) {
        short8 ah, al;
        cvt8(ap + kt * 32, ah, al);
        int t = kt * NT16 + ntile;
        short8 bh = F[(t * 2 + 0) * 64 + lane];
        short8 bl = F[(t * 2 + 1) * 64 + lane];
        T = __builtin_amdgcn_mfma_f32_16x16x32_bf16(ah, bh, T, 0, 0, 0);
        T = __builtin_amdgcn_mfma_f32_16x16x32_bf16(al, bh, T, 0, 0, 0);
        T = __builtin_amdgcn_mfma_f32_16x16x32_bf16(ah, bl, T, 0, 0, 0);
    }
    int o = ntile * 16 + col;
    float b = bias[o];
    float a = (MODE == 0) ? pa[0] : 0.0f;
#pragma unroll
    for (int r = 0; r < 4; ++r) {
        float v = T[r] + b;
        if (MODE == 0) v = (v >= 0.0f) ? v : a * v;
        if (MODE == 1) v = fmaxf(v, 0.0f);
        if (MODE == 2) v = tanhf(v);
        Cout[(size_t)(s0 + quad * 4 + r) * NoutTot + o] = v;
    }
}

// ---------------- head output layer + softmax ----------------
__launch_bounds__(256)
__global__ void k_hout(const float* __restrict__ A, const short* __restrict__ Bf,
                       const float* __restrict__ ob, float* __restrict__ out) {
    __shared__ float sm[16][64];
    __shared__ float smax[16], sinv[16];
    int tid = threadIdx.x, lane = tid & 63, nt = tid >> 6;
    int quad = lane >> 4, col = lane & 15;
    int s0 = blockIdx.x * 16;
    const short8* F = (const short8*)Bf;
    floatx4 T = {0.0f, 0.0f, 0.0f, 0.0f};
    const float* ap = A + (size_t)(s0 + col) * 512 + quad * 8;
#pragma unroll 4
    for (int kt = 0; kt < 16; ++kt) {
        short8 ah, al;
        cvt8(ap + kt * 32, ah, al);
        int t = kt * 4 + nt;
        short8 bh = F[(t * 2 + 0) * 64 + lane];
        short8 bl = F[(t * 2 + 1) * 64 + lane];
        T = __builtin_amdgcn_mfma_f32_16x16x32_bf16(ah, bh, T, 0, 0, 0);
        T = __builtin_amdgcn_mfma_f32_16x16x32_bf16(al, bh, T, 0, 0, 0);
        T = __builtin_amdgcn_mfma_f32_16x16x32_bf16(ah, bl, T, 0, 0, 0);
    }
    int o = nt * 16 + col;
    float b = (o < 54) ? ob[o] : 0.0f;
#pragma unroll
    for (int r = 0; r < 4; ++r)
        sm[quad * 4 + r][o] = (o < 54) ? (T[r] + b) : -1e30f;
    __syncthreads();
    if (tid < 16) {
        float m = -INFINITY;
        for (int j = 0; j < 54; ++j) m = fmaxf(m, sm[tid][j]);
        float s = 0.0f;
        for (int j = 0; j < 54; ++j) s += expf(sm[tid][j] - m);
        smax[tid] = m;
        sinv[tid] = 1.0f / s;
    }
    __syncthreads();
    for (int idx = tid; idx < 16 * 54; idx += 256) {
        int srow = idx / 54, oo = idx % 54;
        out[(size_t)(s0 + srow) * 54 + oo] = expf(sm[srow][oo] - smax[srow]) * sinv[srow];
    }
}

// ---------------- driver ----------------
extern "C" void kernel_launch(void* const* d_in, const int* in_sizes, int n_in,
                              void* d_out, int out_size, void* d_ws, size_t ws_size,
                              hipStream_t stream) {
    const float* node_attr = (const float*)d_in[0];
    const float* edge_attr = (const float*)d_in[1];
    const float* edge_len  = (const float*)d_in[2];
    const int*   src       = (const int*)d_in[3];
    const int*   dst       = (const int*)d_in[4];
    const int*   node_grph = (const int*)d_in[5];
    const float* proj_W    = (const float*)d_in[6];
    const float* proj_b    = (const float*)d_in[7];
    const float* centers   = (const float*)d_in[8];
    const float* beta      = (const float*)d_in[9];
    const float* bond_W    = (const float*)d_in[10];
    const float* bond_b    = (const float*)d_in[11];
    const float* conv_b    = (const float*)d_in[12];
    const float* gru_Wih   = (const float*)d_in[13];
    const float* gru_Whh   = (const float*)d_in[14];
    const float* gru_bih   = (const float*)d_in[15];
    const float* gru_bhh   = (const float*)d_in[16];
    const float* lWih0     = (const float*)d_in[17];
    const float* lWhh0     = (const float*)d_in[18];
    const float* lbih0     = (const float*)d_in[19];
    const float* lbhh0     = (const float*)d_in[20];
    const float* lWih1     = (const float*)d_in[21];
    const float* lWhh1     = (const float*)d_in[22];
    const float* lbih1     = (const float*)d_in[23];
    const float* lbhh1     = (const float*)d_in[24];
    const float* sp_W      = (const float*)d_in[25];
    const float* sp_b      = (const float*)d_in[26];
    const float* prelu_a   = (const float*)d_in[27];
    const float* h0_W1     = (const float*)d_in[28];
    const float* h0_b1     = (const float*)d_in[29];
    const float* h0_W2     = (const float*)d_in[30];
    const float* h0_b2     = (const float*)d_in[31];
    const float* out_W     = (const float*)d_in[32];
    const float* out_b     = (const float*)d_in[33];
    float* out = (float*)d_out;

    float* ws = (float*)d_ws;
    size_t off = 0;
    float* x      = ws + off; off += (size_t)N * 64;
    float* h      = ws + off; off += (size_t)N * 64;
    float* ef_t   = ws + off; off += (size_t)E * 17;   // reused by head after MP loop
    float* agg    = ws + off; off += (size_t)N * 64;
    float* wfrag  = ws + off; off += 17 * 16 * 64 * 8 / 2;
    float* fgI    = ws + off; off += 2 * 64 * 192 / 2;
    float* fgH    = ws + off; off += 2 * 64 * 192 / 2;
    float* lW0T   = ws + off; off += 256 * 512;
    float* lU0T   = ws + off; off += 128 * 512;
    float* lW1T   = ws + off; off += 128 * 512;
    float* lU1T   = ws + off; off += 128 * 512;
    float* h0     = ws + off; off += B * 128;
    float* c0     = ws + off; off += B * 128;
    float* h1     = ws + off; off += B * 128;
    float* c1     = ws + off; off += B * 128;
    float* q_star = ws + off; off += B * 256;
    float* e_buf  = ws + off; off += N;
    unsigned* emax = (unsigned*)(ws + off); off += B;
    int* gs       = (int*)(ws + off); off += B;
    int* ge       = (int*)(ws + off); off += B;

    // head buffers alias the ef_t region (dead after the MP loop)
    short* fsp = (short*)ef_t;
    short* fw1 = (short*)(ef_t + 131072);
    short* fw2 = (short*)(ef_t + 131072 + 262144);
    short* fow = (short*)(ef_t + 131072 + 2 * 262144);
    float* hb1 = ef_t + 131072 + 2 * 262144 + 32768;
    float* hb2 = hb1 + 131072;

    // LSTM weight transposes (PyTorch (out,in) -> (in,out))
    k_transpose<<<(512 * 256 + 255) / 256, 256, 0, stream>>>(lWih0, lW0T, 512, 256);
    k_transpose<<<(512 * 128 + 255) / 256, 256, 0, stream>>>(lWhh0, lU0T, 512, 128);
    k_transpose<<<(512 * 128 + 255) / 256, 256, 0, stream>>>(lWih1, lW1T, 512, 128);
    k_transpose<<<(512 * 128 + 255) / 256, 256, 0, stream>>>(lWhh1, lU1T, 512, 128);

    // bond weights -> split-bf16 MFMA fragment layout
    k_prepW<<<(17 * 4 * 2 * 64 + 255) / 256, 256, 0, stream>>>(bond_W, bond_b, (short*)wfrag);
    // GRU weights -> fragments (PyTorch (192,64) layout, trans=1)
    k_prepB<<<6, 256, 0, stream>>>(gru_Wih, (short*)fgI, 12, 64, 1, 192, 2 * 12 * 64);
    k_prepB<<<6, 256, 0, stream>>>(gru_Whh, (short*)fgH, 12, 64, 1, 192, 2 * 12 * 64);

    // zero LSTM state + q_star (contiguous region: h0,c0,h1,c1,q_star)
    k_fill<<<(4 * B * 128 + B * 256 + 255) / 256, 256, 0, stream>>>(h0, 0.0f, 4 * B * 128 + B * 256);

    k_proj<<<N / 16, 256, 0, stream>>>(node_attr, proj_W, proj_b, x, h);
    k_efeat<<<(E + 255) / 256, 256, 0, stream>>>(edge_attr, edge_len, centers, beta, ef_t);

    k_bounds2<<<(N + 255) / 256, 256, 0, stream>>>(node_grph, gs, ge);

    for (int step = 0; step < 4; ++step) {
        k_agginit<<<(N * 64 + 255) / 256, 256, 0, stream>>>(agg, conv_b);
        k_msg3<<<(E + 127) / 128, 256, 0, stream>>>(h, ef_t, (const short*)wfrag, src, dst, agg);
        k_gru2<<<(N + 31) / 32, 256, 0, stream>>>(agg, h, (const short*)fgI, (const short*)fgH,
                                                  gru_bih, gru_bhh);
    }

    // head fragment prep (ef_t region now dead; weights are (in,out) so trans=0)
    k_prepB<<<64, 256, 0, stream>>>(sp_W, fsp, 32, 512, 0, 512, 8 * 32 * 64);
    k_prepB<<<128, 256, 0, stream>>>(h0_W1, fw1, 32, 512, 0, 512, 16 * 32 * 64);
    k_prepB<<<128, 256, 0, stream>>>(h0_W2, fw2, 32, 512, 0, 512, 16 * 32 * 64);
    k_prepB<<<16, 256, 0, stream>>>(out_W, fow, 4, 54, 0, 54, 16 * 4 * 64);

    for (int it = 0; it < 3; ++it) {
        k_lstm<<<B, 256, 0, stream>>>(h0, c0, h1, c1, q_star,
                                      lW0T, lU0T, lbih0, lbhh0,
                                      lW1T, lU1T, lbih1, lbhh1, emax);
        k_e2<<<(N + 63) / 64, 256, 0, stream>>>(h, x, h1, node_grph, e_buf, emax);
        k_r2<<<B, 256, 0, stream>>>(h, x, e_buf, emax, gs, ge, q_star);
    }

    // head: 3 MFMA GEMM layers + fused output/softmax
    k_hgemm<0><<<dim3(16, 8), 256, 0, stream>>>(q_star, fsp, sp_b, prelu_a, hb1, 256, 32);
    k_hgemm<1><<<dim3(16, 8), 256, 0, stream>>>(hb1, fw1, h0_b1, nullptr, hb2, 512, 32);
    k_hgemm<2><<<dim3(16, 8), 256, 0, stream>>>(hb2, fw2, h0_b2, nullptr, hb1, 512, 32);
    k_hout<<<16, 256, 0, stream>>>(hb1, fow, out_b, out);
}